// Round 1
// baseline (4473.220 us; speedup 1.0000x reference)
//
#include <hip/hip_runtime.h>
#include <math.h>

#define DEV __device__ __forceinline__

DEV float sigmoidf_(float x){ return 1.0f/(1.0f + expf(-x)); }

// ---------------- generic tiny weight-precompute matmul ----------------
__global__ void k_mm_w(const float* __restrict__ A, const float* __restrict__ B,
                       float* __restrict__ C, int M, int N, int K){
    int idx = blockIdx.x*blockDim.x + threadIdx.x;
    if (idx >= M*N) return;
    int m = idx / N, n = idx - m*N;
    float acc = 0.f;
    for (int k=0;k<K;k++) acc += A[m*K+k]*B[k*N+n];
    C[idx] = acc;
}

// ---------------- fa = audio @ faW  (row per block, 128 threads) -------
__global__ void k_rowmm128(const float* __restrict__ X, const float* __restrict__ W,
                           float* __restrict__ Y){
    __shared__ float sx[128];
    int row = blockIdx.x; int t = threadIdx.x;
    sx[t] = X[(size_t)row*128+t];
    __syncthreads();
    float acc=0.f;
    #pragma unroll 8
    for (int k=0;k<128;k++) acc += sx[k]*W[k*128+t];
    Y[(size_t)row*128+t]=acc;
}

// ---------------- a_h = relu(fa@av_aw+b); ga = a_h@av_gw ---------------
__global__ __launch_bounds__(256) void k_ah_ga(
    const float* __restrict__ fa, const float* __restrict__ av_aw,
    const float* __restrict__ av_ab, const float* __restrict__ av_gw,
    float* __restrict__ gGA){
    __shared__ float sfa[128];
    __shared__ float sah[512];
    int bt = blockIdx.x, t = threadIdx.x;
    if (t < 128) sfa[t] = fa[(size_t)bt*128+t];
    __syncthreads();
    for (int u=0;u<2;u++){
        int n = t + u*256;
        float acc = av_ab[n];
        #pragma unroll 8
        for (int k=0;k<128;k++) acc += sfa[k]*av_aw[k*512+n];
        sah[n] = fmaxf(acc, 0.f);
    }
    __syncthreads();
    if (t < 49){
        float acc=0.f;
        for (int k=0;k<512;k++) acc += sah[k]*av_gw[k*49+t];
        gGA[(size_t)bt*49+t] = acc;
    }
}

// ---------------- fused AVGA: v_h GEMM + content + z + softmax + wsum --
__global__ __launch_bounds__(256) void k_avga(
    const float* __restrict__ video, const float* __restrict__ av_vw,
    const float* __restrict__ av_vb, const float* __restrict__ av_v2w,
    const float* __restrict__ av_hw, const float* __restrict__ gGA,
    float* __restrict__ videoT)
{
    __shared__ float sVF[49*516];   // vf tile, stride 516 (float4 aligned, conflict-free)
    __shared__ float sW[2048];      // av_vw 32x64 k-slab; reused as av_v2w 32x49 slab
    __shared__ float sVH[49*68];    // v_h 64-col block
    __shared__ float szp[64*4];
    __shared__ float salpha[64];

    int bt = blockIdx.x;
    int t  = threadIdx.x;
    const float* vf = video + (size_t)bt*49*512;

    // load vf -> LDS (float4)
    for (int idx4 = t; idx4 < 6272; idx4 += 256){
        int p  = idx4 >> 7;         // 128 float4 per row
        int c4 = idx4 & 127;
        float4 v = ((const float4*)vf)[idx4];
        *((float4*)&sVF[p*516 + c4*4]) = v;
    }

    int p  = t >> 2;    // 0..63 (49 active)
    int ds = t & 3;     // quarter group
    bool active = (p < 49);

    float cacc[13];
    #pragma unroll
    for (int j=0;j<13;j++) cacc[j]=0.f;

    for (int db=0; db<8; db++){
        float acc[16];
        #pragma unroll
        for (int j=0;j<16;j++) acc[j]=0.f;

        for (int kb=0;kb<16;kb++){
            __syncthreads();
            // stage av_vw slab rows kb*32..+32, cols db*64..+64
            {
                int i4 = t;
                int r = i4 >> 4, c4 = i4 & 15;
                float4 v = *((const float4*)(av_vw + (size_t)(kb*32 + r)*512 + db*64 + c4*4));
                *((float4*)&sW[r*64 + c4*4]) = v;
                i4 = t + 256; r = i4>>4; c4 = i4&15;
                v = *((const float4*)(av_vw + (size_t)(kb*32 + r)*512 + db*64 + c4*4));
                *((float4*)&sW[r*64 + c4*4]) = v;
            }
            __syncthreads();
            if (active){
                const float* vrow = &sVF[p*516 + kb*32];
                #pragma unroll 8
                for (int k=0;k<32;k++){
                    float vfk = vrow[k];
                    const float4 w0 = *(const float4*)&sW[k*64 + ds*16];
                    const float4 w1 = *(const float4*)&sW[k*64 + ds*16 + 4];
                    const float4 w2 = *(const float4*)&sW[k*64 + ds*16 + 8];
                    const float4 w3 = *(const float4*)&sW[k*64 + ds*16 + 12];
                    acc[0]+=vfk*w0.x; acc[1]+=vfk*w0.y; acc[2]+=vfk*w0.z; acc[3]+=vfk*w0.w;
                    acc[4]+=vfk*w1.x; acc[5]+=vfk*w1.y; acc[6]+=vfk*w1.z; acc[7]+=vfk*w1.w;
                    acc[8]+=vfk*w2.x; acc[9]+=vfk*w2.y; acc[10]+=vfk*w2.z; acc[11]+=vfk*w2.w;
                    acc[12]+=vfk*w3.x; acc[13]+=vfk*w3.y; acc[14]+=vfk*w3.z; acc[15]+=vfk*w3.w;
                }
            }
        }
        // relu(acc + bias) -> sVH
        __syncthreads();
        if (active){
            #pragma unroll
            for (int j=0;j<16;j++){
                int d = db*64 + ds*16 + j;
                sVH[p*68 + ds*16 + j] = fmaxf(acc[j] + av_vb[d], 0.f);
            }
        }
        // content accumulation: content[p][q] += vh[p,d] * av_v2w[d,q]
        for (int dh=0; dh<2; dh++){
            __syncthreads();
            for (int i=t; i<1568; i+=256){
                int r = i/49; int cq = i - r*49;
                sW[i] = av_v2w[(size_t)(db*64 + dh*32 + r)*49 + cq];
            }
            __syncthreads();
            if (active){
                for (int d2=0; d2<32; d2++){
                    float vh = sVH[p*68 + dh*32 + d2];
                    const float* row = &sW[d2*49 + ds*13];
                    #pragma unroll
                    for (int j=0;j<13;j++){
                        if (ds*13+j < 49) cacc[j] += vh * row[j];
                    }
                }
            }
        }
    }

    // z[p] = sum_q tanh(content[p][q] + ga[p]) * hw[q]
    float part = 0.f;
    if (active){
        float ga_p = gGA[(size_t)bt*49 + p];
        #pragma unroll
        for (int j=0;j<13;j++){
            int q = ds*13+j;
            if (q < 49) part += tanhf(cacc[j] + ga_p) * av_hw[q];
        }
    }
    szp[p*4+ds] = part;
    __syncthreads();
    if (t < 64){
        float z = (t<49) ? (szp[t*4]+szp[t*4+1]+szp[t*4+2]+szp[t*4+3]) : -1e30f;
        float m = z;
        for (int off=32; off; off>>=1) m = fmaxf(m, __shfl_xor(m, off));
        float e = (t<49)? expf(z - m) : 0.f;
        float s = e;
        for (int off=32; off; off>>=1) s += __shfl_xor(s, off);
        salpha[t] = e / s;
    }
    __syncthreads();
    // videoT[d] = sum_p alpha[p]*vf[p][d]
    for (int u=0;u<2;u++){
        int d = t + u*256;
        float acc=0.f;
        for (int pp=0;pp<49;pp++) acc += salpha[pp]*sVF[pp*516 + d];
        videoT[(size_t)bt*512 + d] = acc;
    }
}

// ---------------- videoFea = videoT @ fvW  ([512]->[128]) --------------
__global__ void k_rowmm512_128(const float* __restrict__ X, const float* __restrict__ W,
                               float* __restrict__ Y){
    __shared__ float sx[512];
    int row = blockIdx.x, t = threadIdx.x;  // 128 threads
    for (int i=t;i<512;i+=128) sx[i] = X[(size_t)row*512+i];
    __syncthreads();
    float acc=0.f;
    #pragma unroll 8
    for (int k=0;k<512;k++) acc += sx[k]*W[k*128+t];
    Y[(size_t)row*128+t]=acc;
}

// ---------------- xp[c][bt][512] = x @ wih + b -------------------------
__global__ __launch_bounds__(256) void k_xproj(
    const float* __restrict__ fa, const float* __restrict__ vfea,
    const float* __restrict__ la_wih, const float* __restrict__ la_b,
    const float* __restrict__ lv_wih, const float* __restrict__ lv_b,
    float* __restrict__ xp)
{
    int bt = blockIdx.x; int c = blockIdx.y; int t = threadIdx.x;
    const float* x    = (c<2)? fa : vfea;
    const float* wih  = ((c<2)? la_wih : lv_wih) + (size_t)(c&1)*128*512;
    const float* bias = ((c<2)? la_b   : lv_b  ) + (size_t)(c&1)*512;
    __shared__ float sx[128];
    if (t<128) sx[t] = x[(size_t)bt*128+t];
    __syncthreads();
    for (int u=0;u<2;u++){
        int n = t+u*256;
        float acc = bias[n];
        #pragma unroll 8
        for (int k=0;k<128;k++) acc += sx[k]*wih[k*512+n];
        xp[((size_t)c*2560 + bt)*512 + n] = acc;
    }
}

// ---------------- persistent bidirectional LSTMs -----------------------
__global__ __launch_bounds__(256) void k_lstm(
    const float* __restrict__ xp, const float* __restrict__ la_whh,
    const float* __restrict__ lv_whh,
    float* __restrict__ lstm_a, float* __restrict__ lstm_v)
{
    int blk = blockIdx.x;       // 128 blocks
    int c = blk >> 5;           // combo: 0 a-fwd, 1 a-bwd, 2 v-fwd, 3 v-bwd
    int chunk = blk & 31;       // batch chunk of 8
    int t = threadIdx.x;
    int j  = t & 127;
    int bh = t >> 7;            // 0..1, owns 4 samples each
    const float* whh = ((c<2)? la_whh : lv_whh) + (size_t)(c&1)*128*512;
    float* outp = (c<2)? lstm_a : lstm_v;
    int dir = c & 1;

    __shared__ float hbuf[8][128];
    float cc[4] = {0.f,0.f,0.f,0.f};
    for (int i=t;i<1024;i+=256) ((float*)hbuf)[i] = 0.f;
    __syncthreads();

    for (int s=0; s<10; s++){
        int tt = dir ? (9-s) : s;
        float gi[4], gf[4], gg[4], go[4];
        #pragma unroll
        for (int b=0;b<4;b++){
            int gb = chunk*8 + bh*4 + b;
            const float* xrow = xp + ((size_t)c*2560 + gb*10 + tt)*512;
            gi[b]=xrow[j]; gf[b]=xrow[128+j]; gg[b]=xrow[256+j]; go[b]=xrow[384+j];
        }
        #pragma unroll 4
        for (int k=0;k<128;k++){
            float wi = whh[k*512 + j];
            float wf = whh[k*512 + 128 + j];
            float wg = whh[k*512 + 256 + j];
            float wo = whh[k*512 + 384 + j];
            #pragma unroll
            for (int b=0;b<4;b++){
                float hk = hbuf[bh*4+b][k];
                gi[b] += hk*wi; gf[b] += hk*wf; gg[b] += hk*wg; go[b] += hk*wo;
            }
        }
        __syncthreads();   // all reads of h_{t-1} done
        #pragma unroll
        for (int b=0;b<4;b++){
            float i_ = sigmoidf_(gi[b]);
            float f_ = sigmoidf_(gf[b]);
            float g_ = tanhf(gg[b]);
            float o_ = sigmoidf_(go[b]);
            cc[b] = f_*cc[b] + i_*g_;
            float h_ = o_*tanhf(cc[b]);
            hbuf[bh*4+b][j] = h_;
            int gb = chunk*8 + bh*4 + b;
            outp[((size_t)gb*10 + tt)*256 + dir*128 + j] = h_;
        }
        __syncthreads();
    }
}

// ---------------- PSP branch projections -------------------------------
__global__ __launch_bounds__(256) void k_psp1(
    const float* __restrict__ lstm_a, const float* __restrict__ lstm_v,
    const float* __restrict__ vL1, const float* __restrict__ vL2,
    const float* __restrict__ aL1, const float* __restrict__ aL2,
    float* __restrict__ vb1, float* __restrict__ vb2,
    float* __restrict__ ab1, float* __restrict__ ab2)
{
    int bt = blockIdx.x, t = threadIdx.x;
    __shared__ float sa[256], sv[256];
    sa[t] = lstm_a[(size_t)bt*256+t];
    sv[t] = lstm_v[(size_t)bt*256+t];
    __syncthreads();
    float a1=0,a2=0,v1=0,v2=0;
    #pragma unroll 4
    for (int k=0;k<256;k++){
        float av = sa[k], vv = sv[k];
        v1 += vv*vL1[k*256+t];
        v2 += vv*vL2[k*256+t];
        a1 += av*aL1[k*256+t];
        a2 += av*aL2[k*256+t];
    }
    vb1[(size_t)bt*256+t]=fmaxf(v1,0.f); vb2[(size_t)bt*256+t]=fmaxf(v2,0.f);
    ab1[(size_t)bt*256+t]=fmaxf(a1,0.f); ab2[(size_t)bt*256+t]=fmaxf(a2,0.f);
}

// ---------------- per-sample PSP attention + psp outputs ---------------
__global__ __launch_bounds__(256) void k_att(
    const float* __restrict__ lstm_a, const float* __restrict__ lstm_v,
    const float* __restrict__ vb1, const float* __restrict__ vb2,
    const float* __restrict__ ab1, const float* __restrict__ ab2,
    const float* __restrict__ thrp,
    float* __restrict__ vpsp, float* __restrict__ apsp)
{
    int b = blockIdx.x, t = threadIdx.x;
    __shared__ float sV2[2560], sA1[2560], sV1[2560], sA2[2560];
    __shared__ float satt[100], s_v2a[100], s_a2v[100];
    size_t base = (size_t)b*2560;
    for (int i=t;i<2560;i+=256){
        sV2[i]=vb2[base+i]; sA1[i]=ab1[base+i];
        sV1[i]=vb1[base+i]; sA2[i]=ab2[base+i];
    }
    __syncthreads();
    if (t < 100){
        int v = t/10, a = t - v*10;
        float acc=0.f;
        for (int k=0;k<256;k++) acc += sV2[v*256+k]*sA1[a*256+k];
        satt[t] = fmaxf(acc*(1.0f/16.0f), 0.f);
    }
    __syncthreads();
    float thr = thrp[0];
    if (t < 10){
        int v = t;
        float rs=0.f; for(int a=0;a<10;a++) rs += satt[v*10+a];
        float inv = 1.f/(rs+1e-8f);
        float tmp[10]; float rs2=0.f;
        for(int a=0;a<10;a++){ float x = satt[v*10+a]*inv; x = (x>thr)?x:0.f; tmp[a]=x; rs2+=x; }
        float inv2 = 1.f/(rs2+1e-8f);
        for(int a=0;a<10;a++) s_v2a[v*10+a] = tmp[a]*inv2;
    } else if (t>=16 && t<26){
        int a = t-16;
        float cs=0.f; for(int v=0;v<10;v++) cs += satt[v*10+a];
        float inv = 1.f/(cs+1e-8f);
        float tmp[10]; float cs2=0.f;
        for(int v=0;v<10;v++){ float x = satt[v*10+a]*inv; x=(x>thr)?x:0.f; tmp[v]=x; cs2+=x; }
        float inv2 = 1.f/(cs2+1e-8f);
        for(int v=0;v<10;v++) s_a2v[a*10+v] = tmp[v]*inv2;
    }
    __syncthreads();
    for (int v=0;v<10;v++){
        float acc = lstm_v[base + v*256 + t];
        #pragma unroll
        for (int a=0;a<10;a++) acc += s_v2a[v*10+a]*sA2[a*256+t];
        vpsp[base + v*256 + t] = acc;
    }
    for (int a=0;a<10;a++){
        float acc = lstm_a[base + a*256 + t];
        #pragma unroll
        for (int v=0;v<10;v++) acc += s_a2v[a*10+v]*sV1[v*256+t];
        apsp[base + a*256 + t] = acc;
    }
}

// ---------------- final: fc + LN + fuse + cosine + MLP -----------------
DEV float bsum256(float x, volatile float* sp, int t){
    for (int off=32; off; off>>=1) x += __shfl_xor(x, off);
    if ((t&63)==0) sp[t>>6] = x;
    __syncthreads();
    float r = sp[0]+sp[1]+sp[2]+sp[3];
    __syncthreads();
    return r;
}

__global__ __launch_bounds__(256) void k_fin(
    const float* __restrict__ vpsp, const float* __restrict__ apsp,
    const float* __restrict__ vfc, const float* __restrict__ afc,
    const float* __restrict__ ln_g, const float* __restrict__ ln_b,
    const float* __restrict__ L1w, const float* __restrict__ L2w,
    float* __restrict__ dout)
{
    int bt = blockIdx.x, t = threadIdx.x;
    __shared__ float sv[256], sa[256], sf[256], s64[64];
    __shared__ float sp[4];
    sv[t] = vpsp[(size_t)bt*256+t];
    sa[t] = apsp[(size_t)bt*256+t];
    __syncthreads();
    float vv=0.f, aa=0.f;
    #pragma unroll 4
    for (int k=0;k<256;k++){
        vv += sv[k]*vfc[k*256+t];
        aa += sa[k]*afc[k*256+t];
    }
    vv = fmaxf(vv,0.f); aa = fmaxf(aa,0.f);
    // LayerNorm (shared gamma/beta)
    float s1 = bsum256(vv, sp, t);
    float s2 = bsum256(vv*vv, sp, t);
    float mu = s1*(1.f/256.f);
    float var = s2*(1.f/256.f) - mu*mu;
    float vln = (vv-mu)/sqrtf(var+1e-6f)*ln_g[t]+ln_b[t];
    s1 = bsum256(aa, sp, t);
    s2 = bsum256(aa*aa, sp, t);
    mu = s1*(1.f/256.f);
    var = s2*(1.f/256.f) - mu*mu;
    float aln = (aa-mu)/sqrtf(var+1e-6f)*ln_g[t]+ln_b[t];

    float fuse = 0.5f*(vln+aln);
    dout[(size_t)bt*256+t] = fuse;

    float nv2 = bsum256(vln*vln, sp, t);
    float na2 = bsum256(aln*aln, sp, t);
    float dva = bsum256(vln*aln, sp, t);
    if (t==0){
        float nv = fmaxf(sqrtf(nv2), 1e-12f);
        float na = fmaxf(sqrtf(na2), 1e-12f);
        dout[729600 + bt] = dva/(nv*na);
    }
    sf[t]=fuse;
    __syncthreads();
    if (t<64){
        float acc=0.f;
        for (int k=0;k<256;k++) acc += sf[k]*L1w[k*64+t];
        s64[t]=fmaxf(acc,0.f);
    }
    __syncthreads();
    if (t<29){
        float acc=0.f;
        #pragma unroll
        for (int k=0;k<64;k++) acc += s64[k]*L2w[k*29+t];
        dout[655360 + (size_t)bt*29 + t] = acc;
    }
}

// =======================================================================
extern "C" void kernel_launch(void* const* d_in, const int* in_sizes, int n_in,
                              void* d_out, int out_size, void* d_ws, size_t ws_size,
                              hipStream_t stream) {
    const float* audio  = (const float*)d_in[0];
    const float* video  = (const float*)d_in[1];
    const float* thrp   = (const float*)d_in[2];
    const float* fa_w1  = (const float*)d_in[3];
    const float* fa_w2  = (const float*)d_in[4];
    const float* av_aw  = (const float*)d_in[5];
    const float* av_ab  = (const float*)d_in[6];
    const float* av_vw  = (const float*)d_in[7];
    const float* av_vb  = (const float*)d_in[8];
    const float* av_v2w = (const float*)d_in[9];
    const float* av_gw  = (const float*)d_in[10];
    const float* av_hw  = (const float*)d_in[11];
    const float* fv_w1  = (const float*)d_in[12];
    const float* fv_w2  = (const float*)d_in[13];
    const float* la_wih = (const float*)d_in[14];
    const float* la_whh = (const float*)d_in[15];
    const float* la_b   = (const float*)d_in[16];
    const float* lv_wih = (const float*)d_in[17];
    const float* lv_whh = (const float*)d_in[18];
    const float* lv_b   = (const float*)d_in[19];
    const float* vL1    = (const float*)d_in[20];
    const float* vL2    = (const float*)d_in[21];
    const float* aL1    = (const float*)d_in[22];
    const float* aL2    = (const float*)d_in[23];
    const float* vfc    = (const float*)d_in[24];
    const float* afc    = (const float*)d_in[25];
    const float* ln_g   = (const float*)d_in[26];
    const float* ln_b   = (const float*)d_in[27];
    const float* L1w    = (const float*)d_in[28];
    const float* L2w    = (const float*)d_in[29];
    float* dout = (float*)d_out;
    float* ws = (float*)d_ws;

    // workspace layout (float offsets)
    float* faW  = ws;                 // 16384
    float* fvW  = ws + 16384;         // 65536
    float* fa   = ws + 81920;         // 327680
    float* gGA  = ws + 409600;        // 125440
    float* vT   = ws + 535040;        // 1310720
    float* vfea = ws + 1845760;       // 327680
    float* xp   = ws + 2173440;       // 5242880
    float* la   = ws + 7416320;       // 655360
    float* lv   = ws + 8071680;       // 655360
    float* vb1  = ws + 8727040;
    float* vb2  = ws + 9382400;
    float* ab1  = ws + 10037760;
    float* ab2  = ws + 10693120;
    float* vpsp = ws + 11348480;
    float* apsp = ws + 12003840;      // end 12659200 floats (~50.6 MB)

    k_mm_w<<<(128*128+255)/256, 256, 0, stream>>>(fa_w1, fa_w2, faW, 128, 128, 256);
    k_mm_w<<<(512*128+255)/256, 256, 0, stream>>>(fv_w1, fv_w2, fvW, 512, 128, 256);
    k_rowmm128<<<2560, 128, 0, stream>>>(audio, faW, fa);
    k_ah_ga<<<2560, 256, 0, stream>>>(fa, av_aw, av_ab, av_gw, gGA);
    k_avga<<<2560, 256, 0, stream>>>(video, av_vw, av_vb, av_v2w, av_hw, gGA, vT);
    k_rowmm512_128<<<2560, 128, 0, stream>>>(vT, fvW, vfea);
    k_xproj<<<dim3(2560,4), 256, 0, stream>>>(fa, vfea, la_wih, la_b, lv_wih, lv_b, xp);
    k_lstm<<<128, 256, 0, stream>>>(xp, la_whh, lv_whh, la, lv);
    k_psp1<<<2560, 256, 0, stream>>>(la, lv, vL1, vL2, aL1, aL2, vb1, vb2, ab1, ab2);
    k_att<<<256, 256, 0, stream>>>(la, lv, vb1, vb2, ab1, ab2, thrp, vpsp, apsp);
    k_fin<<<2560, 256, 0, stream>>>(vpsp, apsp, vfc, afc, ln_g, ln_b, L1w, L2w, dout);
}

// Round 2
// 2050.685 us; speedup vs baseline: 2.1813x; 2.1813x over previous
//
#include <hip/hip_runtime.h>
#include <math.h>

#define DEV __device__ __forceinline__

DEV float sigmoidf_(float x){ return 1.0f/(1.0f + expf(-x)); }

// ---------------- generic tiny weight-precompute matmul ----------------
__global__ void k_mm_w(const float* __restrict__ A, const float* __restrict__ B,
                       float* __restrict__ C, int M, int N, int K){
    int idx = blockIdx.x*blockDim.x + threadIdx.x;
    if (idx >= M*N) return;
    int m = idx / N, n = idx - m*N;
    float acc = 0.f;
    for (int k=0;k<K;k++) acc += A[m*K+k]*B[k*N+n];
    C[idx] = acc;
}

// ---------------- fa = audio @ faW  (row per block, 128 threads) -------
__global__ void k_rowmm128(const float* __restrict__ X, const float* __restrict__ W,
                           float* __restrict__ Y){
    __shared__ float sx[128];
    int row = blockIdx.x; int t = threadIdx.x;
    sx[t] = X[(size_t)row*128+t];
    __syncthreads();
    float acc=0.f;
    #pragma unroll 8
    for (int k=0;k<128;k++) acc += sx[k]*W[k*128+t];
    Y[(size_t)row*128+t]=acc;
}

// ---------------- a_h = relu(fa@av_aw+b); ga = a_h@av_gw ---------------
__global__ __launch_bounds__(256) void k_ah_ga(
    const float* __restrict__ fa, const float* __restrict__ av_aw,
    const float* __restrict__ av_ab, const float* __restrict__ av_gw,
    float* __restrict__ gGA){
    __shared__ float sfa[128];
    __shared__ float sah[512];
    int bt = blockIdx.x, t = threadIdx.x;
    if (t < 128) sfa[t] = fa[(size_t)bt*128+t];
    __syncthreads();
    for (int u=0;u<2;u++){
        int n = t + u*256;
        float acc = av_ab[n];
        #pragma unroll 8
        for (int k=0;k<128;k++) acc += sfa[k]*av_aw[k*512+n];
        sah[n] = fmaxf(acc, 0.f);
    }
    __syncthreads();
    if (t < 49){
        float acc=0.f;
        for (int k=0;k<512;k++) acc += sah[k]*av_gw[k*49+t];
        gGA[(size_t)bt*49+t] = acc;
    }
}

// ---------------- v_h SGEMM: VH = relu(VF @ vw + vb) -------------------
// M = 25088 (one chunk), N = 512, K = 512. 128x128 tile, 8x8 micro-tile.
__global__ __launch_bounds__(256) void k_vh_sgemm(
    const float* __restrict__ A,    // [M][512]
    const float* __restrict__ B,    // [512][512]
    const float* __restrict__ bias, // [512]
    float* __restrict__ C)          // [M][512]
{
    __shared__ float sA[16][132];   // k-major A tile
    __shared__ float sB[16][132];
    int bid = blockIdx.x;
    int nb = bid & 3;
    int mb = bid >> 2;
    int t = threadIdx.x;
    int tx = t & 15, ty = t >> 4;

    const float* Ab = A + (size_t)mb*128*512;
    const float* Bb = B + nb*128;

    float acc[8][8];
    #pragma unroll
    for (int i=0;i<8;i++)
        #pragma unroll
        for (int j=0;j<8;j++) acc[i][j]=0.f;

    int ar0 = t >> 2;            // 0..63
    int ac0 = (t & 3) * 4;       // 0,4,8,12
    int bk0 = t >> 5;            // 0..7
    int bn0 = (t & 31) * 4;      // 0..124

    float4 pa0, pa1, pb0, pb1;
    // prefetch kb=0
    pa0 = *(const float4*)(Ab + (size_t)ar0*512 + ac0);
    pa1 = *(const float4*)(Ab + (size_t)(ar0+64)*512 + ac0);
    pb0 = *(const float4*)(Bb + (size_t)bk0*512 + bn0);
    pb1 = *(const float4*)(Bb + (size_t)(bk0+8)*512 + bn0);

    for (int kb = 0; kb < 32; ++kb){
        __syncthreads();
        // store staged regs to LDS (A transposed to k-major)
        sA[ac0+0][ar0] = pa0.x; sA[ac0+1][ar0] = pa0.y;
        sA[ac0+2][ar0] = pa0.z; sA[ac0+3][ar0] = pa0.w;
        sA[ac0+0][ar0+64] = pa1.x; sA[ac0+1][ar0+64] = pa1.y;
        sA[ac0+2][ar0+64] = pa1.z; sA[ac0+3][ar0+64] = pa1.w;
        *(float4*)&sB[bk0][bn0]   = pb0;
        *(float4*)&sB[bk0+8][bn0] = pb1;
        __syncthreads();
        if (kb+1 < 32){
            int ko = (kb+1)*16;
            pa0 = *(const float4*)(Ab + (size_t)ar0*512 + ko + ac0);
            pa1 = *(const float4*)(Ab + (size_t)(ar0+64)*512 + ko + ac0);
            pb0 = *(const float4*)(Bb + (size_t)(ko + bk0)*512 + bn0);
            pb1 = *(const float4*)(Bb + (size_t)(ko + bk0 + 8)*512 + bn0);
        }
        #pragma unroll
        for (int k=0;k<16;k++){
            float a[8], b[8];
            *(float4*)&a[0] = *(const float4*)&sA[k][ty*8];
            *(float4*)&a[4] = *(const float4*)&sA[k][ty*8+4];
            *(float4*)&b[0] = *(const float4*)&sB[k][tx*8];
            *(float4*)&b[4] = *(const float4*)&sB[k][tx*8+4];
            #pragma unroll
            for (int i=0;i<8;i++)
                #pragma unroll
                for (int j=0;j<8;j++) acc[i][j] += a[i]*b[j];
        }
    }

    float bv[8];
    #pragma unroll
    for (int j=0;j<8;j++) bv[j] = bias[nb*128 + tx*8 + j];
    #pragma unroll
    for (int i=0;i<8;i++){
        size_t row = (size_t)(mb*128 + ty*8 + i);
        float4 o0, o1;
        o0.x = fmaxf(acc[i][0]+bv[0],0.f); o0.y = fmaxf(acc[i][1]+bv[1],0.f);
        o0.z = fmaxf(acc[i][2]+bv[2],0.f); o0.w = fmaxf(acc[i][3]+bv[3],0.f);
        o1.x = fmaxf(acc[i][4]+bv[4],0.f); o1.y = fmaxf(acc[i][5]+bv[5],0.f);
        o1.z = fmaxf(acc[i][6]+bv[6],0.f); o1.w = fmaxf(acc[i][7]+bv[7],0.f);
        *(float4*)(C + row*512 + nb*128 + tx*8)     = o0;
        *(float4*)(C + row*512 + nb*128 + tx*8 + 4) = o1;
    }
}

// ---------------- content GEMM: Ct = VH @ v2w  ([M][512]x[512][49]) ----
// 64-row tile, 4x4 micro-tile (13x16 active thread grid of 256).
__global__ __launch_bounds__(256) void k_content(
    const float* __restrict__ VH,   // [25088][512]
    const float* __restrict__ v2w,  // [512][49]
    float* __restrict__ Ct)         // [25088][49]
{
    __shared__ float sA[16][68];    // [k][m]
    __shared__ float sB[16][64];    // [k][q] (49 valid, rest 0)
    int mb = blockIdx.x;            // 392
    int t = threadIdx.x;
    int tx = t & 15, ty = t >> 4;

    float acc[4][4];
    #pragma unroll
    for (int i=0;i<4;i++)
        #pragma unroll
        for (int j=0;j<4;j++) acc[i][j]=0.f;

    int ar = t >> 2;           // 0..63
    int ac = (t & 3) * 4;

    for (int kb = 0; kb < 32; ++kb){
        __syncthreads();
        float4 a = *(const float4*)(VH + (size_t)(mb*64 + ar)*512 + kb*16 + ac);
        sA[ac+0][ar]=a.x; sA[ac+1][ar]=a.y; sA[ac+2][ar]=a.z; sA[ac+3][ar]=a.w;
        for (int i = t; i < 16*64; i += 256){
            int k = i >> 6, n = i & 63;
            sB[k][n] = (n < 49) ? v2w[(size_t)(kb*16 + k)*49 + n] : 0.f;
        }
        __syncthreads();
        #pragma unroll
        for (int k=0;k<16;k++){
            float4 a4 = *(const float4*)&sA[k][ty*4];
            float4 b4 = *(const float4*)&sB[k][tx*4];
            float av[4] = {a4.x,a4.y,a4.z,a4.w};
            float bv[4] = {b4.x,b4.y,b4.z,b4.w};
            #pragma unroll
            for (int i=0;i<4;i++)
                #pragma unroll
                for (int j=0;j<4;j++) acc[i][j] += av[i]*bv[j];
        }
    }
    if (tx < 13){
        #pragma unroll
        for (int i=0;i<4;i++){
            size_t row = (size_t)(mb*64 + ty*4 + i);
            #pragma unroll
            for (int j=0;j<4;j++){
                int q = tx*4 + j;
                if (q < 49) Ct[row*49 + q] = acc[i][j];
            }
        }
    }
}

// ---------------- z, softmax, videoT per (b,t) -------------------------
__global__ __launch_bounds__(256) void k_zvt(
    const float* __restrict__ Ct,    // chunk [512*49][49]
    const float* __restrict__ gGA,   // chunk [512][49]
    const float* __restrict__ hw,    // [49]
    const float* __restrict__ video, // chunk [512*49][512]
    float* __restrict__ vT)          // chunk [512][512]
{
    int bt = blockIdx.x; int t = threadIdx.x;
    __shared__ float sC[49][52];
    __shared__ float salpha[64];
    for (int i = t; i < 49*49; i += 256){
        int p = i / 49, q = i - p*49;
        sC[p][q] = Ct[(size_t)(bt*49 + p)*49 + q];
    }
    __syncthreads();
    if (t < 64){
        float z = -1e30f;
        if (t < 49){
            float ga = gGA[(size_t)bt*49 + t];
            float acc = 0.f;
            for (int q=0;q<49;q++) acc += tanhf(sC[t][q] + ga) * hw[q];
            z = acc;
        }
        float m = z;
        for (int off=32; off; off>>=1) m = fmaxf(m, __shfl_xor(m, off));
        float e = (t<49)? expf(z - m) : 0.f;
        float s = e;
        for (int off=32; off; off>>=1) s += __shfl_xor(s, off);
        salpha[t] = e / s;
    }
    __syncthreads();
    const float* vb = video + (size_t)bt*49*512;
    float a0=0.f, a1=0.f;
    for (int p=0;p<49;p++){
        float al = salpha[p];
        a0 += al * vb[(size_t)p*512 + t];
        a1 += al * vb[(size_t)p*512 + t + 256];
    }
    vT[(size_t)bt*512 + t] = a0;
    vT[(size_t)bt*512 + t + 256] = a1;
}

// ---------------- videoFea = videoT @ fvW  ([512]->[128]) --------------
__global__ void k_rowmm512_128(const float* __restrict__ X, const float* __restrict__ W,
                               float* __restrict__ Y){
    __shared__ float sx[512];
    int row = blockIdx.x, t = threadIdx.x;  // 128 threads
    for (int i=t;i<512;i+=128) sx[i] = X[(size_t)row*512+i];
    __syncthreads();
    float acc=0.f;
    #pragma unroll 8
    for (int k=0;k<512;k++) acc += sx[k]*W[k*128+t];
    Y[(size_t)row*128+t]=acc;
}

// ---------------- xp[c][bt][512] = x @ wih + b -------------------------
__global__ __launch_bounds__(256) void k_xproj(
    const float* __restrict__ fa, const float* __restrict__ vfea,
    const float* __restrict__ la_wih, const float* __restrict__ la_b,
    const float* __restrict__ lv_wih, const float* __restrict__ lv_b,
    float* __restrict__ xp)
{
    int bt = blockIdx.x; int c = blockIdx.y; int t = threadIdx.x;
    const float* x    = (c<2)? fa : vfea;
    const float* wih  = ((c<2)? la_wih : lv_wih) + (size_t)(c&1)*128*512;
    const float* bias = ((c<2)? la_b   : lv_b  ) + (size_t)(c&1)*512;
    __shared__ float sx[128];
    if (t<128) sx[t] = x[(size_t)bt*128+t];
    __syncthreads();
    for (int u=0;u<2;u++){
        int n = t+u*256;
        float acc = bias[n];
        #pragma unroll 8
        for (int k=0;k<128;k++) acc += sx[k]*wih[k*512+n];
        xp[((size_t)c*2560 + bt)*512 + n] = acc;
    }
}

// ---------------- persistent bidirectional LSTMs -----------------------
__global__ __launch_bounds__(256) void k_lstm(
    const float* __restrict__ xp, const float* __restrict__ la_whh,
    const float* __restrict__ lv_whh,
    float* __restrict__ lstm_a, float* __restrict__ lstm_v)
{
    int blk = blockIdx.x;       // 128 blocks
    int c = blk >> 5;           // combo: 0 a-fwd, 1 a-bwd, 2 v-fwd, 3 v-bwd
    int chunk = blk & 31;       // batch chunk of 8
    int t = threadIdx.x;
    int j  = t & 127;
    int bh = t >> 7;            // 0..1, owns 4 samples each
    const float* whh = ((c<2)? la_whh : lv_whh) + (size_t)(c&1)*128*512;
    float* outp = (c<2)? lstm_a : lstm_v;
    int dir = c & 1;

    __shared__ float hbuf[8][128];
    float cc[4] = {0.f,0.f,0.f,0.f};
    for (int i=t;i<1024;i+=256) ((float*)hbuf)[i] = 0.f;
    __syncthreads();

    for (int s=0; s<10; s++){
        int tt = dir ? (9-s) : s;
        float gi[4], gf[4], gg[4], go[4];
        #pragma unroll
        for (int b=0;b<4;b++){
            int gb = chunk*8 + bh*4 + b;
            const float* xrow = xp + ((size_t)c*2560 + gb*10 + tt)*512;
            gi[b]=xrow[j]; gf[b]=xrow[128+j]; gg[b]=xrow[256+j]; go[b]=xrow[384+j];
        }
        #pragma unroll 4
        for (int k=0;k<128;k++){
            float wi = whh[k*512 + j];
            float wf = whh[k*512 + 128 + j];
            float wg = whh[k*512 + 256 + j];
            float wo = whh[k*512 + 384 + j];
            #pragma unroll
            for (int b=0;b<4;b++){
                float hk = hbuf[bh*4+b][k];
                gi[b] += hk*wi; gf[b] += hk*wf; gg[b] += hk*wg; go[b] += hk*wo;
            }
        }
        __syncthreads();   // all reads of h_{t-1} done
        #pragma unroll
        for (int b=0;b<4;b++){
            float i_ = sigmoidf_(gi[b]);
            float f_ = sigmoidf_(gf[b]);
            float g_ = tanhf(gg[b]);
            float o_ = sigmoidf_(go[b]);
            cc[b] = f_*cc[b] + i_*g_;
            float h_ = o_*tanhf(cc[b]);
            hbuf[bh*4+b][j] = h_;
            int gb = chunk*8 + bh*4 + b;
            outp[((size_t)gb*10 + tt)*256 + dir*128 + j] = h_;
        }
        __syncthreads();
    }
}

// ---------------- PSP branch projections -------------------------------
__global__ __launch_bounds__(256) void k_psp1(
    const float* __restrict__ lstm_a, const float* __restrict__ lstm_v,
    const float* __restrict__ vL1, const float* __restrict__ vL2,
    const float* __restrict__ aL1, const float* __restrict__ aL2,
    float* __restrict__ vb1, float* __restrict__ vb2,
    float* __restrict__ ab1, float* __restrict__ ab2)
{
    int bt = blockIdx.x, t = threadIdx.x;
    __shared__ float sa[256], sv[256];
    sa[t] = lstm_a[(size_t)bt*256+t];
    sv[t] = lstm_v[(size_t)bt*256+t];
    __syncthreads();
    float a1=0,a2=0,v1=0,v2=0;
    #pragma unroll 4
    for (int k=0;k<256;k++){
        float av = sa[k], vv = sv[k];
        v1 += vv*vL1[k*256+t];
        v2 += vv*vL2[k*256+t];
        a1 += av*aL1[k*256+t];
        a2 += av*aL2[k*256+t];
    }
    vb1[(size_t)bt*256+t]=fmaxf(v1,0.f); vb2[(size_t)bt*256+t]=fmaxf(v2,0.f);
    ab1[(size_t)bt*256+t]=fmaxf(a1,0.f); ab2[(size_t)bt*256+t]=fmaxf(a2,0.f);
}

// ---------------- per-sample PSP attention + psp outputs ---------------
__global__ __launch_bounds__(256) void k_att(
    const float* __restrict__ lstm_a, const float* __restrict__ lstm_v,
    const float* __restrict__ vb1, const float* __restrict__ vb2,
    const float* __restrict__ ab1, const float* __restrict__ ab2,
    const float* __restrict__ thrp,
    float* __restrict__ vpsp, float* __restrict__ apsp)
{
    int b = blockIdx.x, t = threadIdx.x;
    __shared__ float sV2[2560], sA1[2560], sV1[2560], sA2[2560];
    __shared__ float satt[100], s_v2a[100], s_a2v[100];
    size_t base = (size_t)b*2560;
    for (int i=t;i<2560;i+=256){
        sV2[i]=vb2[base+i]; sA1[i]=ab1[base+i];
        sV1[i]=vb1[base+i]; sA2[i]=ab2[base+i];
    }
    __syncthreads();
    if (t < 100){
        int v = t/10, a = t - v*10;
        float acc=0.f;
        for (int k=0;k<256;k++) acc += sV2[v*256+k]*sA1[a*256+k];
        satt[t] = fmaxf(acc*(1.0f/16.0f), 0.f);
    }
    __syncthreads();
    float thr = thrp[0];
    if (t < 10){
        int v = t;
        float rs=0.f; for(int a=0;a<10;a++) rs += satt[v*10+a];
        float inv = 1.f/(rs+1e-8f);
        float tmp[10]; float rs2=0.f;
        for(int a=0;a<10;a++){ float x = satt[v*10+a]*inv; x = (x>thr)?x:0.f; tmp[a]=x; rs2+=x; }
        float inv2 = 1.f/(rs2+1e-8f);
        for(int a=0;a<10;a++) s_v2a[v*10+a] = tmp[a]*inv2;
    } else if (t>=16 && t<26){
        int a = t-16;
        float cs=0.f; for(int v=0;v<10;v++) cs += satt[v*10+a];
        float inv = 1.f/(cs+1e-8f);
        float tmp[10]; float cs2=0.f;
        for(int v=0;v<10;v++){ float x = satt[v*10+a]*inv; x=(x>thr)?x:0.f; tmp[v]=x; cs2+=x; }
        float inv2 = 1.f/(cs2+1e-8f);
        for(int v=0;v<10;v++) s_a2v[a*10+v] = tmp[v]*inv2;
    }
    __syncthreads();
    for (int v=0;v<10;v++){
        float acc = lstm_v[base + v*256 + t];
        #pragma unroll
        for (int a=0;a<10;a++) acc += s_v2a[v*10+a]*sA2[a*256+t];
        vpsp[base + v*256 + t] = acc;
    }
    for (int a=0;a<10;a++){
        float acc = lstm_a[base + a*256 + t];
        #pragma unroll
        for (int v=0;v<10;v++) acc += s_a2v[a*10+v]*sV1[v*256+t];
        apsp[base + a*256 + t] = acc;
    }
}

// ---------------- final: fc + LN + fuse + cosine + MLP -----------------
DEV float bsum256(float x, volatile float* sp, int t){
    for (int off=32; off; off>>=1) x += __shfl_xor(x, off);
    if ((t&63)==0) sp[t>>6] = x;
    __syncthreads();
    float r = sp[0]+sp[1]+sp[2]+sp[3];
    __syncthreads();
    return r;
}

__global__ __launch_bounds__(256) void k_fin(
    const float* __restrict__ vpsp, const float* __restrict__ apsp,
    const float* __restrict__ vfc, const float* __restrict__ afc,
    const float* __restrict__ ln_g, const float* __restrict__ ln_b,
    const float* __restrict__ L1w, const float* __restrict__ L2w,
    float* __restrict__ dout)
{
    int bt = blockIdx.x, t = threadIdx.x;
    __shared__ float sv[256], sa[256], sf[256], s64[64];
    __shared__ float sp[4];
    sv[t] = vpsp[(size_t)bt*256+t];
    sa[t] = apsp[(size_t)bt*256+t];
    __syncthreads();
    float vv=0.f, aa=0.f;
    #pragma unroll 4
    for (int k=0;k<256;k++){
        vv += sv[k]*vfc[k*256+t];
        aa += sa[k]*afc[k*256+t];
    }
    vv = fmaxf(vv,0.f); aa = fmaxf(aa,0.f);
    // LayerNorm (shared gamma/beta)
    float s1 = bsum256(vv, sp, t);
    float s2 = bsum256(vv*vv, sp, t);
    float mu = s1*(1.f/256.f);
    float var = s2*(1.f/256.f) - mu*mu;
    float vln = (vv-mu)/sqrtf(var+1e-6f)*ln_g[t]+ln_b[t];
    s1 = bsum256(aa, sp, t);
    s2 = bsum256(aa*aa, sp, t);
    mu = s1*(1.f/256.f);
    var = s2*(1.f/256.f) - mu*mu;
    float aln = (aa-mu)/sqrtf(var+1e-6f)*ln_g[t]+ln_b[t];

    float fuse = 0.5f*(vln+aln);
    dout[(size_t)bt*256+t] = fuse;

    float nv2 = bsum256(vln*vln, sp, t);
    float na2 = bsum256(aln*aln, sp, t);
    float dva = bsum256(vln*aln, sp, t);
    if (t==0){
        float nv = fmaxf(sqrtf(nv2), 1e-12f);
        float na = fmaxf(sqrtf(na2), 1e-12f);
        dout[729600 + bt] = dva/(nv*na);
    }
    sf[t]=fuse;
    __syncthreads();
    if (t<64){
        float acc=0.f;
        for (int k=0;k<256;k++) acc += sf[k]*L1w[k*64+t];
        s64[t]=fmaxf(acc,0.f);
    }
    __syncthreads();
    if (t<29){
        float acc=0.f;
        #pragma unroll
        for (int k=0;k<64;k++) acc += s64[k]*L2w[k*29+t];
        dout[655360 + (size_t)bt*29 + t] = acc;
    }
}

// =======================================================================
extern "C" void kernel_launch(void* const* d_in, const int* in_sizes, int n_in,
                              void* d_out, int out_size, void* d_ws, size_t ws_size,
                              hipStream_t stream) {
    const float* audio  = (const float*)d_in[0];
    const float* video  = (const float*)d_in[1];
    const float* thrp   = (const float*)d_in[2];
    const float* fa_w1  = (const float*)d_in[3];
    const float* fa_w2  = (const float*)d_in[4];
    const float* av_aw  = (const float*)d_in[5];
    const float* av_ab  = (const float*)d_in[6];
    const float* av_vw  = (const float*)d_in[7];
    const float* av_vb  = (const float*)d_in[8];
    const float* av_v2w = (const float*)d_in[9];
    const float* av_gw  = (const float*)d_in[10];
    const float* av_hw  = (const float*)d_in[11];
    const float* fv_w1  = (const float*)d_in[12];
    const float* fv_w2  = (const float*)d_in[13];
    const float* la_wih = (const float*)d_in[14];
    const float* la_whh = (const float*)d_in[15];
    const float* la_b   = (const float*)d_in[16];
    const float* lv_wih = (const float*)d_in[17];
    const float* lv_whh = (const float*)d_in[18];
    const float* lv_b   = (const float*)d_in[19];
    const float* vL1    = (const float*)d_in[20];
    const float* vL2    = (const float*)d_in[21];
    const float* aL1    = (const float*)d_in[22];
    const float* aL2    = (const float*)d_in[23];
    const float* vfc    = (const float*)d_in[24];
    const float* afc    = (const float*)d_in[25];
    const float* ln_g   = (const float*)d_in[26];
    const float* ln_b   = (const float*)d_in[27];
    const float* L1w    = (const float*)d_in[28];
    const float* L2w    = (const float*)d_in[29];
    float* dout = (float*)d_out;
    float* ws = (float*)d_ws;

    // workspace layout (float offsets)
    float* faW  = ws;                 // 16384
    float* fvW  = ws + 16384;         // 65536
    float* fa   = ws + 81920;         // 327680
    float* gGA  = ws + 409600;        // 125440
    float* vT   = ws + 535040;        // 1310720
    float* vfea = ws + 1845760;       // 327680
    float* xp   = ws + 2173440;       // 5242880
    float* la   = ws + 7416320;       // 655360
    float* lv   = ws + 8071680;       // 655360
    float* vb1  = ws + 8727040;
    float* vb2  = ws + 9382400;
    float* ab1  = ws + 10037760;
    float* ab2  = ws + 10693120;
    float* vpsp = ws + 11348480;
    float* apsp = ws + 12003840;
    float* VH   = ws + 12659200;      // 12845056 (25088 x 512, one chunk)
    float* Ct   = ws + 25504256;      // 1229312  (25088 x 49,  one chunk)
                                      // end 26733568 floats (~107 MB)

    k_mm_w<<<(128*128+255)/256, 256, 0, stream>>>(fa_w1, fa_w2, faW, 128, 128, 256);
    k_mm_w<<<(512*128+255)/256, 256, 0, stream>>>(fv_w1, fv_w2, fvW, 512, 128, 256);
    k_rowmm128<<<2560, 128, 0, stream>>>(audio, faW, fa);
    k_ah_ga<<<2560, 256, 0, stream>>>(fa, av_aw, av_ab, av_gw, gGA);

    // AVGA pipeline, chunked 5x over (b,t): 512 bt = 25088 rows per chunk
    for (int c = 0; c < 5; ++c){
        const float* vid_c = video + (size_t)c*25088*512;
        k_vh_sgemm<<<196*4, 256, 0, stream>>>(vid_c, av_vw, av_vb, VH);
        k_content<<<392, 256, 0, stream>>>(VH, av_v2w, Ct);
        k_zvt<<<512, 256, 0, stream>>>(Ct, gGA + (size_t)c*512*49, av_hw,
                                       vid_c, vT + (size_t)c*512*512);
    }

    k_rowmm512_128<<<2560, 128, 0, stream>>>(vT, fvW, vfea);
    k_xproj<<<dim3(2560,4), 256, 0, stream>>>(fa, vfea, la_wih, la_b, lv_wih, lv_b, xp);
    k_lstm<<<128, 256, 0, stream>>>(xp, la_whh, lv_whh, la, lv);
    k_psp1<<<2560, 256, 0, stream>>>(la, lv, vL1, vL2, aL1, aL2, vb1, vb2, ab1, ab2);
    k_att<<<256, 256, 0, stream>>>(la, lv, vb1, vb2, ab1, ab2, thrp, vpsp, apsp);
    k_fin<<<2560, 256, 0, stream>>>(vpsp, apsp, vfc, afc, ln_g, ln_b, L1w, L2w, dout);
}

// Round 3
// 967.478 us; speedup vs baseline: 4.6236x; 2.1196x over previous
//
#include <hip/hip_runtime.h>
#include <math.h>

#define DEV __device__ __forceinline__

typedef _Float16 f16x8 __attribute__((ext_vector_type(8)));
typedef _Float16 f16x4 __attribute__((ext_vector_type(4)));
typedef float    f32x4 __attribute__((ext_vector_type(4)));

DEV float sigmoidf_(float x){ return 1.0f/(1.0f + expf(-x)); }

// ---------------- generic tiny weight-precompute matmul ----------------
__global__ void k_mm_w(const float* __restrict__ A, const float* __restrict__ B,
                       float* __restrict__ C, int M, int N, int K){
    int idx = blockIdx.x*blockDim.x + threadIdx.x;
    if (idx >= M*N) return;
    int m = idx / N, n = idx - m*N;
    float acc = 0.f;
    for (int k=0;k<K;k++) acc += A[m*K+k]*B[k*N+n];
    C[idx] = acc;
}

// ---------------- fa = audio @ faW ------------------------------------
__global__ void k_rowmm128(const float* __restrict__ X, const float* __restrict__ W,
                           float* __restrict__ Y){
    __shared__ float sx[128];
    int row = blockIdx.x; int t = threadIdx.x;
    sx[t] = X[(size_t)row*128+t];
    __syncthreads();
    float acc=0.f;
    #pragma unroll 8
    for (int k=0;k<128;k++) acc += sx[k]*W[k*128+t];
    Y[(size_t)row*128+t]=acc;
}

// ---------------- a_h = relu(fa@av_aw+b); ga = a_h@av_gw ---------------
__global__ __launch_bounds__(256) void k_ah_ga(
    const float* __restrict__ fa, const float* __restrict__ av_aw,
    const float* __restrict__ av_ab, const float* __restrict__ av_gw,
    float* __restrict__ gGA){
    __shared__ float sfa[128];
    __shared__ float sah[512];
    int bt = blockIdx.x, t = threadIdx.x;
    if (t < 128) sfa[t] = fa[(size_t)bt*128+t];
    __syncthreads();
    for (int u=0;u<2;u++){
        int n = t + u*256;
        float acc = av_ab[n];
        #pragma unroll 8
        for (int k=0;k<128;k++) acc += sfa[k]*av_aw[k*512+n];
        sah[n] = fmaxf(acc, 0.f);
    }
    __syncthreads();
    if (t < 49){
        float acc=0.f;
        for (int k=0;k<512;k++) acc += sah[k]*av_gw[k*49+t];
        gGA[(size_t)bt*49+t] = acc;
    }
}

// ---------------- pack av_vw into MFMA B-fragment layout, f16 hi/lo ----
// ushort idx = kt*16384 + nf*512 + kg*128 + l16*8 + j
//   k = kt*32 + kg*8 + j   (K dim, 512)
//   n = nf*16 + l16        (N dim, 512)
__global__ void k_bpack(const float* __restrict__ Wsrc,
                        _Float16* __restrict__ Hh, _Float16* __restrict__ Hl){
    int o = blockIdx.x*256 + threadIdx.x;   // 262144
    int j = o & 7, l16 = (o>>3)&15, kg = (o>>7)&3, nf = (o>>9)&31, kt = o>>14;
    int k = kt*32 + kg*8 + j, n = nf*16 + l16;
    float x = Wsrc[(size_t)k*512 + n];
    _Float16 h = (_Float16)x;
    Hh[o] = h; Hl[o] = (_Float16)(x - (float)h);
}

// ---------------- pack v2w into per-lane B-fragment layout -------------
// ushort idx = kbg*2048 + qf*512 + kg*128 + l16*8 + j
//   k = kbg*32 + kg*8 + j  (K dim = 512, the VH n-dim)
//   q = qf*16 + l16        (N dim, 49 valid, zero-padded to 64)
__global__ void k_bpack2(const float* __restrict__ v2w,
                         _Float16* __restrict__ Hh, _Float16* __restrict__ Hl){
    int o = blockIdx.x*256 + threadIdx.x;   // 32768
    int j = o & 7, l16 = (o>>3)&15, kg = (o>>7)&3, qf = (o>>9)&3, kbg = o>>11;
    int k = kbg*32 + kg*8 + j, q = qf*16 + l16;
    float x = (q < 49) ? v2w[(size_t)k*49 + q] : 0.f;
    _Float16 h = (_Float16)x;
    Hh[o] = h; Hl[o] = (_Float16)(x - (float)h);
}

// ---------------- fused AVGA MFMA: VH GEMM + content partials ----------
DEV void cvt4_(float4 v, f16x4& hv, f16x4& lv){
    hv[0]=(_Float16)v.x; lv[0]=(_Float16)(v.x-(float)hv[0]);
    hv[1]=(_Float16)v.y; lv[1]=(_Float16)(v.y-(float)hv[1]);
    hv[2]=(_Float16)v.z; lv[2]=(_Float16)(v.z-(float)hv[2]);
    hv[3]=(_Float16)v.w; lv[3]=(_Float16)(v.w-(float)hv[3]);
}

#define MFMA16(a,b,c) __builtin_amdgcn_mfma_f32_16x16x32_f16(a,b,c,0,0,0)

__global__ __launch_bounds__(256,2) void k_avga_mfma(
    const float* __restrict__ A,       // video [125440][512]
    const _Float16* __restrict__ Bh, const _Float16* __restrict__ Bl,
    const float* __restrict__ bias,    // av_vb [512]
    const _Float16* __restrict__ Wh, const _Float16* __restrict__ Wl,
    float* __restrict__ Cpart)         // [2][125440][49]
{
    __shared__ __align__(16) char sB[2][32768];   // per buf: hi 16KB + lo 16KB
    __shared__ __align__(16) char sA[2][8192];    // per buf: hi 4KB + lo 4KB
    int bid = blockIdx.x;
    int nb = bid & 1, mb = bid >> 1;
    int t = threadIdx.x;
    int lane = t & 63, w = t >> 6;
    int row0 = mb * 64;

    // A staging coords (thread t loads rows am, am+32; 4 consecutive k)
    int am = t >> 3;              // 0..31
    int ak = (t & 7) * 4;         // 0..28
    int aoff1 = ((am>>4)*4 + (ak>>3))*256 + (am&15)*16 + (ak&7)*2;
    int am2 = am + 32;
    int aoff2 = ((am2>>4)*4 + (ak>>3))*256 + (am2&15)*16 + (ak&7)*2;
    const float* Arow1 = A + (size_t)(row0 + am )*512 + ak;
    const float* Arow2 = A + (size_t)(row0 + am2)*512 + ak;

    const f32x4 vzero = {0.f,0.f,0.f,0.f};
    f32x4 acc[4][4];
    #pragma unroll
    for (int p=0;p<4;p++)
        #pragma unroll
        for (int q=0;q<4;q++) acc[p][q] = vzero;

    float4 pa0, pa1;
    uint4 breg[8];

    // ---- prologue: stage kt=0 into buf 0 ----
    pa0 = *(const float4*)(Arow1);
    pa1 = *(const float4*)(Arow2);
    {
        const uint4* gh = (const uint4*)((const char*)Bh + (size_t)nb*16384);
        const uint4* gl = (const uint4*)((const char*)Bl + (size_t)nb*16384);
        uint4* d = (uint4*)&sB[0][0];
        #pragma unroll
        for (int r=0;r<4;r++) d[r*256+t]      = gh[r*256+t];
        #pragma unroll
        for (int r=0;r<4;r++) d[1024+r*256+t] = gl[r*256+t];
        f16x4 hv, lv;
        char* h = &sA[0][0];
        cvt4_(pa0, hv, lv);
        *(f16x4*)(h + aoff1) = hv; *(f16x4*)(h + 4096 + aoff1) = lv;
        cvt4_(pa1, hv, lv);
        *(f16x4*)(h + aoff2) = hv; *(f16x4*)(h + 4096 + aoff2) = lv;
    }
    __syncthreads();

    int lb = lane * 16;
    // ---- main K loop: 16 steps of BK=32 ----
    for (int kt = 0; kt < 16; ++kt){
        int cur = kt & 1;
        bool more = (kt < 15);
        if (more){
            pa0 = *(const float4*)(Arow1 + (kt+1)*32);
            pa1 = *(const float4*)(Arow2 + (kt+1)*32);
            const uint4* gh = (const uint4*)((const char*)Bh + (size_t)(kt+1)*32768 + nb*16384);
            const uint4* gl = (const uint4*)((const char*)Bl + (size_t)(kt+1)*32768 + nb*16384);
            #pragma unroll
            for (int r=0;r<4;r++) breg[r]   = gh[r*256+t];
            #pragma unroll
            for (int r=0;r<4;r++) breg[4+r] = gl[r*256+t];
        }
        const char* aB = &sA[cur][0];
        const char* bB = &sB[cur][0];
        f16x8 ah[4], al[4];
        #pragma unroll
        for (int p=0;p<4;p++){
            ah[p] = *(const f16x8*)(aB + p*1024 + lb);
            al[p] = *(const f16x8*)(aB + 4096 + p*1024 + lb);
        }
        #pragma unroll
        for (int q=0;q<4;q++){
            int nfl = w*4 + q;
            f16x8 bh  = *(const f16x8*)(bB + nfl*1024 + lb);
            f16x8 bl2 = *(const f16x8*)(bB + 16384 + nfl*1024 + lb);
            #pragma unroll
            for (int p=0;p<4;p++){
                acc[p][q] = MFMA16(ah[p], bh,  acc[p][q]);
                acc[p][q] = MFMA16(ah[p], bl2, acc[p][q]);
                acc[p][q] = MFMA16(al[p], bh,  acc[p][q]);
            }
        }
        if (more){
            uint4* d = (uint4*)&sB[cur^1][0];
            #pragma unroll
            for (int r=0;r<4;r++) d[r*256+t]      = breg[r];
            #pragma unroll
            for (int r=0;r<4;r++) d[1024+r*256+t] = breg[4+r];
            char* h = &sA[cur^1][0];
            f16x4 hv, lv;
            cvt4_(pa0, hv, lv);
            *(f16x4*)(h + aoff1) = hv; *(f16x4*)(h + 4096 + aoff1) = lv;
            cvt4_(pa1, hv, lv);
            *(f16x4*)(h + aoff2) = hv; *(f16x4*)(h + 4096 + aoff2) = lv;
        }
        __syncthreads();
    }

    // ---- epilogue: bias+relu, split VH to f16 in A-frag layout --------
    int l16 = lane & 15, lq = lane >> 4;
    float bv[4];
    #pragma unroll
    for (int q=0;q<4;q++) bv[q] = bias[nb*256 + w*64 + q*16 + l16];
    char* vh = ((char*)&sB[0][0]) + w*16384;   // per-wave 16KB: hi 8KB + lo 8KB
    #pragma unroll
    for (int p=0;p<4;p++)
        #pragma unroll
        for (int q=0;q<4;q++){
            int offbase = (q>>1)*4096 + p*1024 + ((q&1)*2 + (l16>>3))*256 + (l16&7)*2;
            #pragma unroll
            for (int r=0;r<4;r++){
                float x = fmaxf(acc[p][q][r] + bv[q], 0.f);
                _Float16 hh = (_Float16)x;
                _Float16 ll = (_Float16)(x - (float)hh);
                int off = offbase + (lq*4 + r)*16;
                *(_Float16*)(vh + off)        = hh;
                *(_Float16*)(vh + 8192 + off) = ll;
            }
        }

    // ---- content partial: cacc = VH_wave(64x64) @ v2w_slice(64x64) ----
    f32x4 cacc[4][4];
    #pragma unroll
    for (int p=0;p<4;p++)
        #pragma unroll
        for (int q=0;q<4;q++) cacc[p][q] = vzero;
    int kbgbase = nb*8 + w*2;
    #pragma unroll
    for (int k2=0;k2<2;k2++){
        f16x8 vhh[4], vhl[4];
        #pragma unroll
        for (int p=0;p<4;p++){
            vhh[p] = *(const f16x8*)(vh + k2*4096 + p*1024 + lb);
            vhl[p] = *(const f16x8*)(vh + 8192 + k2*4096 + p*1024 + lb);
        }
        #pragma unroll
        for (int qf=0;qf<4;qf++){
            f16x8 wh = *(const f16x8*)((const char*)Wh + (size_t)(kbgbase+k2)*4096 + qf*1024 + lb);
            f16x8 wl = *(const f16x8*)((const char*)Wl + (size_t)(kbgbase+k2)*4096 + qf*1024 + lb);
            #pragma unroll
            for (int p=0;p<4;p++){
                cacc[p][qf] = MFMA16(vhh[p], wh, cacc[p][qf]);
                cacc[p][qf] = MFMA16(vhh[p], wl, cacc[p][qf]);
                cacc[p][qf] = MFMA16(vhl[p], wh, cacc[p][qf]);
            }
        }
    }
    __syncthreads();
    // write per-wave f32 partial (64x64) and reduce across 4 waves
    float* pw = (float*)(((char*)&sB[0][0]) + w*16384);
    #pragma unroll
    for (int p=0;p<4;p++)
        #pragma unroll
        for (int qf=0;qf<4;qf++)
            #pragma unroll
            for (int r=0;r<4;r++)
                pw[(p*16 + lq*4 + r)*64 + qf*16 + l16] = cacc[p][qf][r];
    __syncthreads();
    const float* rb = (const float*)&sB[0][0];
    for (int i = t; i < 64*49; i += 256){
        int m = i / 49, q = i - m*49;
        int o = m*64 + q;
        float s = rb[o] + rb[4096+o] + rb[8192+o] + rb[12288+o];
        Cpart[(size_t)nb*6146560 + (size_t)(row0+m)*49 + q] = s;
    }
}

// ---------------- z, softmax, videoT per (b,t) -------------------------
__global__ __launch_bounds__(256) void k_zvt(
    const float* __restrict__ Ct0, const float* __restrict__ Ct1,
    const float* __restrict__ gGA, const float* __restrict__ hw,
    const float* __restrict__ video, float* __restrict__ vT)
{
    int bt = blockIdx.x; int t = threadIdx.x;
    __shared__ float sC[49][52];
    __shared__ float salpha[64];
    for (int i = t; i < 49*49; i += 256){
        int p = i / 49, q = i - p*49;
        size_t idx = (size_t)(bt*49 + p)*49 + q;
        sC[p][q] = Ct0[idx] + Ct1[idx];
    }
    __syncthreads();
    if (t < 64){
        float z = -1e30f;
        if (t < 49){
            float ga = gGA[(size_t)bt*49 + t];
            float acc = 0.f;
            for (int q=0;q<49;q++) acc += tanhf(sC[t][q] + ga) * hw[q];
            z = acc;
        }
        float m = z;
        for (int off=32; off; off>>=1) m = fmaxf(m, __shfl_xor(m, off));
        float e = (t<49)? expf(z - m) : 0.f;
        float s = e;
        for (int off=32; off; off>>=1) s += __shfl_xor(s, off);
        salpha[t] = e / s;
    }
    __syncthreads();
    const float* vb = video + (size_t)bt*49*512;
    float a0=0.f, a1=0.f;
    for (int p=0;p<49;p++){
        float al = salpha[p];
        a0 += al * vb[(size_t)p*512 + t];
        a1 += al * vb[(size_t)p*512 + t + 256];
    }
    vT[(size_t)bt*512 + t] = a0;
    vT[(size_t)bt*512 + t + 256] = a1;
}

// ---------------- videoFea = videoT @ fvW ------------------------------
__global__ void k_rowmm512_128(const float* __restrict__ X, const float* __restrict__ W,
                               float* __restrict__ Y){
    __shared__ float sx[512];
    int row = blockIdx.x, t = threadIdx.x;  // 128 threads
    for (int i=t;i<512;i+=128) sx[i] = X[(size_t)row*512+i];
    __syncthreads();
    float acc=0.f;
    #pragma unroll 8
    for (int k=0;k<512;k++) acc += sx[k]*W[k*128+t];
    Y[(size_t)row*128+t]=acc;
}

// ---------------- xp[c][bt][512] = x @ wih + b -------------------------
__global__ __launch_bounds__(256) void k_xproj(
    const float* __restrict__ fa, const float* __restrict__ vfea,
    const float* __restrict__ la_wih, const float* __restrict__ la_b,
    const float* __restrict__ lv_wih, const float* __restrict__ lv_b,
    float* __restrict__ xp)
{
    int bt = blockIdx.x; int c = blockIdx.y; int t = threadIdx.x;
    const float* x    = (c<2)? fa : vfea;
    const float* wih  = ((c<2)? la_wih : lv_wih) + (size_t)(c&1)*128*512;
    const float* bias = ((c<2)? la_b   : lv_b  ) + (size_t)(c&1)*512;
    __shared__ float sx[128];
    if (t<128) sx[t] = x[(size_t)bt*128+t];
    __syncthreads();
    for (int u=0;u<2;u++){
        int n = t+u*256;
        float acc = bias[n];
        #pragma unroll 8
        for (int k=0;k<128;k++) acc += sx[k]*wih[k*512+n];
        xp[((size_t)c*2560 + bt)*512 + n] = acc;
    }
}

// ---------------- persistent bidirectional LSTMs -----------------------
__global__ __launch_bounds__(256) void k_lstm(
    const float* __restrict__ xp, const float* __restrict__ la_whh,
    const float* __restrict__ lv_whh,
    float* __restrict__ lstm_a, float* __restrict__ lstm_v)
{
    int blk = blockIdx.x;
    int c = blk >> 5;
    int chunk = blk & 31;
    int t = threadIdx.x;
    int j  = t & 127;
    int bh = t >> 7;
    const float* whh = ((c<2)? la_whh : lv_whh) + (size_t)(c&1)*128*512;
    float* outp = (c<2)? lstm_a : lstm_v;
    int dir = c & 1;

    __shared__ float hbuf[8][128];
    float cc[4] = {0.f,0.f,0.f,0.f};
    for (int i=t;i<1024;i+=256) ((float*)hbuf)[i] = 0.f;
    __syncthreads();

    for (int s=0; s<10; s++){
        int tt = dir ? (9-s) : s;
        float gi[4], gf[4], gg[4], go[4];
        #pragma unroll
        for (int b=0;b<4;b++){
            int gb = chunk*8 + bh*4 + b;
            const float* xrow = xp + ((size_t)c*2560 + gb*10 + tt)*512;
            gi[b]=xrow[j]; gf[b]=xrow[128+j]; gg[b]=xrow[256+j]; go[b]=xrow[384+j];
        }
        #pragma unroll 4
        for (int k=0;k<128;k++){
            float wi = whh[k*512 + j];
            float wf = whh[k*512 + 128 + j];
            float wg = whh[k*512 + 256 + j];
            float wo = whh[k*512 + 384 + j];
            #pragma unroll
            for (int b=0;b<4;b++){
                float hk = hbuf[bh*4+b][k];
                gi[b] += hk*wi; gf[b] += hk*wf; gg[b] += hk*wg; go[b] += hk*wo;
            }
        }
        __syncthreads();
        #pragma unroll
        for (int b=0;b<4;b++){
            float i_ = sigmoidf_(gi[b]);
            float f_ = sigmoidf_(gf[b]);
            float g_ = tanhf(gg[b]);
            float o_ = sigmoidf_(go[b]);
            cc[b] = f_*cc[b] + i_*g_;
            float h_ = o_*tanhf(cc[b]);
            hbuf[bh*4+b][j] = h_;
            int gb = chunk*8 + bh*4 + b;
            outp[((size_t)gb*10 + tt)*256 + dir*128 + j] = h_;
        }
        __syncthreads();
    }
}

// ---------------- PSP branch projections -------------------------------
__global__ __launch_bounds__(256) void k_psp1(
    const float* __restrict__ lstm_a, const float* __restrict__ lstm_v,
    const float* __restrict__ vL1, const float* __restrict__ vL2,
    const float* __restrict__ aL1, const float* __restrict__ aL2,
    float* __restrict__ vb1, float* __restrict__ vb2,
    float* __restrict__ ab1, float* __restrict__ ab2)
{
    int bt = blockIdx.x, t = threadIdx.x;
    __shared__ float sa[256], sv[256];
    sa[t] = lstm_a[(size_t)bt*256+t];
    sv[t] = lstm_v[(size_t)bt*256+t];
    __syncthreads();
    float a1=0,a2=0,v1=0,v2=0;
    #pragma unroll 4
    for (int k=0;k<256;k++){
        float av = sa[k], vv = sv[k];
        v1 += vv*vL1[k*256+t];
        v2 += vv*vL2[k*256+t];
        a1 += av*aL1[k*256+t];
        a2 += av*aL2[k*256+t];
    }
    vb1[(size_t)bt*256+t]=fmaxf(v1,0.f); vb2[(size_t)bt*256+t]=fmaxf(v2,0.f);
    ab1[(size_t)bt*256+t]=fmaxf(a1,0.f); ab2[(size_t)bt*256+t]=fmaxf(a2,0.f);
}

// ---------------- per-sample PSP attention + psp outputs ---------------
__global__ __launch_bounds__(256) void k_att(
    const float* __restrict__ lstm_a, const float* __restrict__ lstm_v,
    const float* __restrict__ vb1, const float* __restrict__ vb2,
    const float* __restrict__ ab1, const float* __restrict__ ab2,
    const float* __restrict__ thrp,
    float* __restrict__ vpsp, float* __restrict__ apsp)
{
    int b = blockIdx.x, t = threadIdx.x;
    __shared__ float sV2[2560], sA1[2560], sV1[2560], sA2[2560];
    __shared__ float satt[100], s_v2a[100], s_a2v[100];
    size_t base = (size_t)b*2560;
    for (int i=t;i<2560;i+=256){
        sV2[i]=vb2[base+i]; sA1[i]=ab1[base+i];
        sV1[i]=vb1[base+i]; sA2[i]=ab2[base+i];
    }
    __syncthreads();
    if (t < 100){
        int v = t/10, a = t - v*10;
        float acc=0.f;
        for (int k=0;k<256;k++) acc += sV2[v*256+k]*sA1[a*256+k];
        satt[t] = fmaxf(acc*(1.0f/16.0f), 0.f);
    }
    __syncthreads();
    float thr = thrp[0];
    if (t < 10){
        int v = t;
        float rs=0.f; for(int a=0;a<10;a++) rs += satt[v*10+a];
        float inv = 1.f/(rs+1e-8f);
        float tmp[10]; float rs2=0.f;
        for(int a=0;a<10;a++){ float x = satt[v*10+a]*inv; x = (x>thr)?x:0.f; tmp[a]=x; rs2+=x; }
        float inv2 = 1.f/(rs2+1e-8f);
        for(int a=0;a<10;a++) s_v2a[v*10+a] = tmp[a]*inv2;
    } else if (t>=16 && t<26){
        int a = t-16;
        float cs=0.f; for(int v=0;v<10;v++) cs += satt[v*10+a];
        float inv = 1.f/(cs+1e-8f);
        float tmp[10]; float cs2=0.f;
        for(int v=0;v<10;v++){ float x = satt[v*10+a]*inv; x=(x>thr)?x:0.f; tmp[v]=x; cs2+=x; }
        float inv2 = 1.f/(cs2+1e-8f);
        for(int v=0;v<10;v++) s_a2v[a*10+v] = tmp[v]*inv2;
    }
    __syncthreads();
    for (int v=0;v<10;v++){
        float acc = lstm_v[base + v*256 + t];
        #pragma unroll
        for (int a=0;a<10;a++) acc += s_v2a[v*10+a]*sA2[a*256+t];
        vpsp[base + v*256 + t] = acc;
    }
    for (int a=0;a<10;a++){
        float acc = lstm_a[base + a*256 + t];
        #pragma unroll
        for (int v=0;v<10;v++) acc += s_a2v[a*10+v]*sV1[v*256+t];
        apsp[base + a*256 + t] = acc;
    }
}

// ---------------- final: fc + LN + fuse + cosine + MLP -----------------
DEV float bsum256(float x, volatile float* sp, int t){
    for (int off=32; off; off>>=1) x += __shfl_xor(x, off);
    if ((t&63)==0) sp[t>>6] = x;
    __syncthreads();
    float r = sp[0]+sp[1]+sp[2]+sp[3];
    __syncthreads();
    return r;
}

__global__ __launch_bounds__(256) void k_fin(
    const float* __restrict__ vpsp, const float* __restrict__ apsp,
    const float* __restrict__ vfc, const float* __restrict__ afc,
    const float* __restrict__ ln_g, const float* __restrict__ ln_b,
    const float* __restrict__ L1w, const float* __restrict__ L2w,
    float* __restrict__ dout)
{
    int bt = blockIdx.x, t = threadIdx.x;
    __shared__ float sv[256], sa[256], sf[256], s64[64];
    __shared__ float sp[4];
    sv[t] = vpsp[(size_t)bt*256+t];
    sa[t] = apsp[(size_t)bt*256+t];
    __syncthreads();
    float vv=0.f, aa=0.f;
    #pragma unroll 4
    for (int k=0;k<256;k++){
        vv += sv[k]*vfc[k*256+t];
        aa += sa[k]*afc[k*256+t];
    }
    vv = fmaxf(vv,0.f); aa = fmaxf(aa,0.f);
    float s1 = bsum256(vv, sp, t);
    float s2 = bsum256(vv*vv, sp, t);
    float mu = s1*(1.f/256.f);
    float var = s2*(1.f/256.f) - mu*mu;
    float vln = (vv-mu)/sqrtf(var+1e-6f)*ln_g[t]+ln_b[t];
    s1 = bsum256(aa, sp, t);
    s2 = bsum256(aa*aa, sp, t);
    mu = s1*(1.f/256.f);
    var = s2*(1.f/256.f) - mu*mu;
    float aln = (aa-mu)/sqrtf(var+1e-6f)*ln_g[t]+ln_b[t];

    float fuse = 0.5f*(vln+aln);
    dout[(size_t)bt*256+t] = fuse;

    float nv2 = bsum256(vln*vln, sp, t);
    float na2 = bsum256(aln*aln, sp, t);
    float dva = bsum256(vln*aln, sp, t);
    if (t==0){
        float nv = fmaxf(sqrtf(nv2), 1e-12f);
        float na = fmaxf(sqrtf(na2), 1e-12f);
        dout[729600 + bt] = dva/(nv*na);
    }
    sf[t]=fuse;
    __syncthreads();
    if (t<64){
        float acc=0.f;
        for (int k=0;k<256;k++) acc += sf[k]*L1w[k*64+t];
        s64[t]=fmaxf(acc,0.f);
    }
    __syncthreads();
    if (t<29){
        float acc=0.f;
        #pragma unroll
        for (int k=0;k<64;k++) acc += s64[k]*L2w[k*29+t];
        dout[655360 + (size_t)bt*29 + t] = acc;
    }
}

// =======================================================================
extern "C" void kernel_launch(void* const* d_in, const int* in_sizes, int n_in,
                              void* d_out, int out_size, void* d_ws, size_t ws_size,
                              hipStream_t stream) {
    const float* audio  = (const float*)d_in[0];
    const float* video  = (const float*)d_in[1];
    const float* thrp   = (const float*)d_in[2];
    const float* fa_w1  = (const float*)d_in[3];
    const float* fa_w2  = (const float*)d_in[4];
    const float* av_aw  = (const float*)d_in[5];
    const float* av_ab  = (const float*)d_in[6];
    const float* av_vw  = (const float*)d_in[7];
    const float* av_vb  = (const float*)d_in[8];
    const float* av_v2w = (const float*)d_in[9];
    const float* av_gw  = (const float*)d_in[10];
    const float* av_hw  = (const float*)d_in[11];
    const float* fv_w1  = (const float*)d_in[12];
    const float* fv_w2  = (const float*)d_in[13];
    const float* la_wih = (const float*)d_in[14];
    const float* la_whh = (const float*)d_in[15];
    const float* la_b   = (const float*)d_in[16];
    const float* lv_wih = (const float*)d_in[17];
    const float* lv_whh = (const float*)d_in[18];
    const float* lv_b   = (const float*)d_in[19];
    const float* vL1    = (const float*)d_in[20];
    const float* vL2    = (const float*)d_in[21];
    const float* aL1    = (const float*)d_in[22];
    const float* aL2    = (const float*)d_in[23];
    const float* vfc    = (const float*)d_in[24];
    const float* afc    = (const float*)d_in[25];
    const float* ln_g   = (const float*)d_in[26];
    const float* ln_b   = (const float*)d_in[27];
    const float* L1w    = (const float*)d_in[28];
    const float* L2w    = (const float*)d_in[29];
    float* dout = (float*)d_out;
    float* ws = (float*)d_ws;

    // workspace layout (float offsets)
    float* faW  = ws;                 // 16384
    float* fvW  = ws + 16384;         // 65536
    float* fa   = ws + 81920;         // 327680
    float* gGA  = ws + 409600;        // 125440
    float* vT   = ws + 535040;        // 1310720
    float* vfea = ws + 1845760;       // 327680
    float* xp   = ws + 2173440;       // 5242880
    float* la   = ws + 7416320;       // 655360
    float* lv   = ws + 8071680;       // 655360
    float* vb1  = ws + 8727040;
    float* vb2  = ws + 9382400;
    float* ab1  = ws + 10037760;
    float* ab2  = ws + 10693120;
    float* vpsp = ws + 11348480;
    float* apsp = ws + 12003840;
    _Float16* Bh = (_Float16*)(ws + 12659200);  // 262144 halves
    _Float16* Bl = (_Float16*)(ws + 12790272);
    _Float16* Wh = (_Float16*)(ws + 12921344);  // 32768 halves
    _Float16* Wl = (_Float16*)(ws + 12937728);
    float* Cp   = ws + 12954112;      // 2 x 6146560 -> end 25247232 (~101 MB)

    k_mm_w<<<(128*128+255)/256, 256, 0, stream>>>(fa_w1, fa_w2, faW, 128, 128, 256);
    k_mm_w<<<(512*128+255)/256, 256, 0, stream>>>(fv_w1, fv_w2, fvW, 512, 128, 256);
    k_bpack<<<1024, 256, 0, stream>>>(av_vw, Bh, Bl);
    k_bpack2<<<128, 256, 0, stream>>>(av_v2w, Wh, Wl);
    k_rowmm128<<<2560, 128, 0, stream>>>(audio, faW, fa);
    k_ah_ga<<<2560, 256, 0, stream>>>(fa, av_aw, av_ab, av_gw, gGA);

    k_avga_mfma<<<3920, 256, 0, stream>>>(video, Bh, Bl, av_vb, Wh, Wl, Cp);
    k_zvt<<<2560, 256, 0, stream>>>(Cp, Cp + 6146560, gGA, av_hw, video, vT);

    k_rowmm512_128<<<2560, 128, 0, stream>>>(vT, fvW, vfea);
    k_xproj<<<dim3(2560,4), 256, 0, stream>>>(fa, vfea, la_wih, la_b, lv_wih, lv_b, xp);
    k_lstm<<<128, 256, 0, stream>>>(xp, la_whh, lv_whh, la, lv);
    k_psp1<<<2560, 256, 0, stream>>>(la, lv, vL1, vL2, aL1, aL2, vb1, vb2, ab1, ab2);
    k_att<<<256, 256, 0, stream>>>(la, lv, vb1, vb2, ab1, ab2, thrp, vpsp, apsp);
    k_fin<<<2560, 256, 0, stream>>>(vpsp, apsp, vfc, afc, ln_g, ln_b, L1w, L2w, dout);
}

// Round 4
// 791.038 us; speedup vs baseline: 5.6549x; 1.2230x over previous
//
#include <hip/hip_runtime.h>
#include <math.h>

#define DEV __device__ __forceinline__

typedef _Float16 f16x8 __attribute__((ext_vector_type(8)));
typedef _Float16 f16x4 __attribute__((ext_vector_type(4)));
typedef float    f32x4 __attribute__((ext_vector_type(4)));

DEV float sigmoidf_(float x){ return 1.0f/(1.0f + expf(-x)); }

DEV float wred64(float x){
    #pragma unroll
    for (int off=32; off; off>>=1) x += __shfl_xor(x, off);
    return x;
}

// ---------------- prep: faW, fvW, bpack(av_vw), bpack2(v2w) ------------
__global__ __launch_bounds__(256) void k_prep(
    const float* __restrict__ fa_w1, const float* __restrict__ fa_w2, float* __restrict__ faW,
    const float* __restrict__ fv_w1, const float* __restrict__ fv_w2, float* __restrict__ fvW,
    const float* __restrict__ av_vw, _Float16* __restrict__ Bh, _Float16* __restrict__ Bl,
    const float* __restrict__ v2w, _Float16* __restrict__ Wh, _Float16* __restrict__ Wl)
{
    int bid = blockIdx.x, t = threadIdx.x;
    if (bid < 64){                       // faW = fa_w1 @ fa_w2 [128,128] K=256
        int idx = bid*256+t; int m = idx>>7, n = idx&127;
        float acc=0.f;
        for (int k=0;k<256;k++) acc += fa_w1[m*256+k]*fa_w2[k*128+n];
        faW[idx]=acc;
    } else if (bid < 320){               // fvW = fv_w1 @ fv_w2 [512,128] K=256
        int idx = (bid-64)*256+t; int m = idx>>7, n = idx&127;
        float acc=0.f;
        for (int k=0;k<256;k++) acc += fv_w1[m*256+k]*fv_w2[k*128+n];
        fvW[idx]=acc;
    } else if (bid < 1344){              // pack av_vw into B-frag layout
        int o = (bid-320)*256+t;         // 262144
        int j = o & 7, l16 = (o>>3)&15, kg = (o>>7)&3, nf = (o>>9)&31, kt = o>>14;
        int k = kt*32 + kg*8 + j, n = nf*16 + l16;
        float x = av_vw[(size_t)k*512 + n];
        _Float16 h = (_Float16)x;
        Bh[o] = h; Bl[o] = (_Float16)(x - (float)h);
    } else {                             // pack v2w
        int o = (bid-1344)*256+t;        // 32768
        int j = o & 7, l16 = (o>>3)&15, kg = (o>>7)&3, qf = (o>>9)&3, kbg = o>>11;
        int k = kbg*32 + kg*8 + j, q = qf*16 + l16;
        float x = (q < 49) ? v2w[(size_t)k*49 + q] : 0.f;
        _Float16 h = (_Float16)x;
        Wh[o] = h; Wl[o] = (_Float16)(x - (float)h);
    }
}

// ---------------- fused fa + a_h + ga, 4 bt per block ------------------
__global__ __launch_bounds__(256) void k_faga(
    const float* __restrict__ audio, const float* __restrict__ faW,
    const float* __restrict__ av_aw, const float* __restrict__ av_ab,
    const float* __restrict__ av_gw, float* __restrict__ fa, float* __restrict__ gGA)
{
    int b0 = blockIdx.x*4; int t = threadIdx.x;
    __shared__ float sau[4][128], sfa[4][128], sah[4][512];
    for (int i=t;i<512;i+=256){ int bt=i>>7,k=i&127; sau[bt][k]=audio[(size_t)(b0+bt)*128+k]; }
    __syncthreads();
    for (int u=0;u<2;u++){
        int i=t+u*256, bt=i>>7, n=i&127;
        float acc=0.f;
        for (int k4=0;k4<32;k4++){
            float4 x4=*(const float4*)&sau[bt][k4*4];
            acc+=x4.x*faW[(k4*4)*128+n]+x4.y*faW[(k4*4+1)*128+n]
                +x4.z*faW[(k4*4+2)*128+n]+x4.w*faW[(k4*4+3)*128+n];
        }
        sfa[bt][n]=acc; fa[(size_t)(b0+bt)*128+n]=acc;
    }
    __syncthreads();
    for (int u=0;u<2;u++){
        int n=t+u*256;
        float bv=av_ab[n];
        float acc[4]={bv,bv,bv,bv};
        for (int k4=0;k4<32;k4++){
            float w0=av_aw[(k4*4)*512+n], w1=av_aw[(k4*4+1)*512+n],
                  w2=av_aw[(k4*4+2)*512+n], w3=av_aw[(k4*4+3)*512+n];
            #pragma unroll
            for (int bt=0;bt<4;bt++){
                float4 x4=*(const float4*)&sfa[bt][k4*4];
                acc[bt]+=x4.x*w0+x4.y*w1+x4.z*w2+x4.w*w3;
            }
        }
        #pragma unroll
        for (int bt=0;bt<4;bt++) sah[bt][n]=fmaxf(acc[bt],0.f);
    }
    __syncthreads();
    if (t<196){
        int bt=t/49, q=t-bt*49;
        float acc=0.f;
        for (int k=0;k<512;k++) acc+=sah[bt][k]*av_gw[k*49+q];
        gGA[(size_t)(b0+bt)*49+q]=acc;
    }
}

// ---------------- fused AVGA MFMA: VH GEMM + content -------------------
DEV void cvt4_(float4 v, f16x4& hv, f16x4& lv){
    hv[0]=(_Float16)v.x; lv[0]=(_Float16)(v.x-(float)hv[0]);
    hv[1]=(_Float16)v.y; lv[1]=(_Float16)(v.y-(float)hv[1]);
    hv[2]=(_Float16)v.z; lv[2]=(_Float16)(v.z-(float)hv[2]);
    hv[3]=(_Float16)v.w; lv[3]=(_Float16)(v.w-(float)hv[3]);
}

#define MFMA16(a,b,c) __builtin_amdgcn_mfma_f32_16x16x32_f16(a,b,c,0,0,0)

__global__ __launch_bounds__(256,3) void k_avga_mfma(
    const float* __restrict__ A,       // video [125440][512]
    const _Float16* __restrict__ Bh, const _Float16* __restrict__ Bl,
    const float* __restrict__ bias,    // av_vb [512]
    const _Float16* __restrict__ Wh, const _Float16* __restrict__ Wl,
    float* __restrict__ Cpart)         // [2][125440][49]
{
    __shared__ __align__(16) char sA[2][8192];    // A tile hi+lo, dbuf
    __shared__ __align__(16) char sVH[2][16384];  // two time-shared VH bufs
    int bid = blockIdx.x;
    int nb = bid & 1, mb = bid >> 1;
    int t = threadIdx.x;
    int lane = t & 63, w = t >> 6;
    int row0 = mb * 64;
    int l16 = lane & 15, lq = lane >> 4;
    int lb = lane * 16;

    // A staging coords
    int am = t >> 3, ak = (t & 7) * 4;
    int aoff1 = ((am>>4)*4 + (ak>>3))*256 + (am&15)*16 + (ak&7)*2;
    int am2 = am + 32;
    int aoff2 = ((am2>>4)*4 + (ak>>3))*256 + (am2&15)*16 + (ak&7)*2;
    const float* Arow1 = A + (size_t)(row0 + am )*512 + ak;
    const float* Arow2 = A + (size_t)(row0 + am2)*512 + ak;

    const f32x4 vzero = {0.f,0.f,0.f,0.f};
    f32x4 acc[4][4];
    #pragma unroll
    for (int p=0;p<4;p++)
        #pragma unroll
        for (int q=0;q<4;q++) acc[p][q] = vzero;

    float4 pa0, pa1;
    // prologue: stage kt=0
    pa0 = *(const float4*)(Arow1);
    pa1 = *(const float4*)(Arow2);
    {
        f16x4 hv, lv;
        char* h = &sA[0][0];
        cvt4_(pa0, hv, lv);
        *(f16x4*)(h + aoff1) = hv; *(f16x4*)(h + 4096 + aoff1) = lv;
        cvt4_(pa1, hv, lv);
        *(f16x4*)(h + aoff2) = hv; *(f16x4*)(h + 4096 + aoff2) = lv;
    }
    __syncthreads();

    // main K loop: 16 x BK=32; B frags direct from global (L2-resident)
    for (int kt = 0; kt < 16; ++kt){
        int cur = kt & 1;
        bool more = (kt < 15);
        if (more){
            pa0 = *(const float4*)(Arow1 + (kt+1)*32);
            pa1 = *(const float4*)(Arow2 + (kt+1)*32);
        }
        const char* aB = &sA[cur][0];
        f16x8 ah[4], al[4];
        #pragma unroll
        for (int p=0;p<4;p++){
            ah[p] = *(const f16x8*)(aB + p*1024 + lb);
            al[p] = *(const f16x8*)(aB + 4096 + p*1024 + lb);
        }
        #pragma unroll
        for (int q=0;q<4;q++){
            size_t bo = (size_t)kt*16384 + (size_t)(nb*16 + w*4 + q)*512 + lane*8;
            f16x8 bh  = *(const f16x8*)(Bh + bo);
            f16x8 bl2 = *(const f16x8*)(Bl + bo);
            #pragma unroll
            for (int p=0;p<4;p++){
                acc[p][q] = MFMA16(ah[p], bh,  acc[p][q]);
                acc[p][q] = MFMA16(ah[p], bl2, acc[p][q]);
                acc[p][q] = MFMA16(al[p], bh,  acc[p][q]);
            }
        }
        if (more){
            char* h = &sA[cur^1][0];
            f16x4 hv, lv;
            cvt4_(pa0, hv, lv);
            *(f16x4*)(h + aoff1) = hv; *(f16x4*)(h + 4096 + aoff1) = lv;
            cvt4_(pa1, hv, lv);
            *(f16x4*)(h + aoff2) = hv; *(f16x4*)(h + 4096 + aoff2) = lv;
        }
        __syncthreads();
    }

    // ---- epilogue ----
    float bv[4];
    #pragma unroll
    for (int q=0;q<4;q++) bv[q] = bias[nb*256 + w*64 + q*16 + l16];

    f32x4 cacc[4];
    #pragma unroll
    for (int qf=0;qf<4;qf++) cacc[qf] = vzero;

    // two phases: waves {0,1} then {2,3} publish VH; all waves consume
    #pragma unroll
    for (int ph=0; ph<2; ++ph){
        if ((w>>1) == ph){
            char* buf = &sVH[w&1][0];
            #pragma unroll
            for (int p=0;p<4;p++)
                #pragma unroll
                for (int q=0;q<4;q++){
                    int offbase = (q>>1)*4096 + p*1024 + ((q&1)*2 + (l16>>3))*256 + (l16&7)*2;
                    #pragma unroll
                    for (int r=0;r<4;r++){
                        float x = fmaxf(acc[p][q][r] + bv[q], 0.f);
                        _Float16 hh = (_Float16)x;
                        _Float16 ll = (_Float16)(x - (float)hh);
                        int off = offbase + (lq*4 + r)*16;
                        *(_Float16*)(buf + off)        = hh;
                        *(_Float16*)(buf + 8192 + off) = ll;
                    }
                }
        }
        __syncthreads();
        #pragma unroll
        for (int jb=0; jb<2; ++jb){
            int j = ph*2 + jb;
            const char* buf = &sVH[jb][0];
            #pragma unroll
            for (int k2=0;k2<2;k2++){
                f16x8 vhh = *(const f16x8*)(buf + k2*4096 + w*1024 + lb);
                f16x8 vhl = *(const f16x8*)(buf + 8192 + k2*4096 + w*1024 + lb);
                int kbg = nb*8 + j*2 + k2;
                #pragma unroll
                for (int qf=0;qf<4;qf++){
                    size_t wo = (size_t)kbg*2048 + qf*512 + lane*8;
                    f16x8 wh = *(const f16x8*)(Wh + wo);
                    f16x8 wl = *(const f16x8*)(Wl + wo);
                    cacc[qf] = MFMA16(vhh, wh, cacc[qf]);
                    cacc[qf] = MFMA16(vhh, wl, cacc[qf]);
                    cacc[qf] = MFMA16(vhl, wh, cacc[qf]);
                }
            }
        }
        __syncthreads();
    }

    // write content: wave w owns m-rows 16w..16w+15
    #pragma unroll
    for (int qf=0;qf<4;qf++){
        int col = qf*16 + l16;
        if (col < 49){
            #pragma unroll
            for (int r=0;r<4;r++){
                Cpart[(size_t)nb*6146560 + (size_t)(row0 + w*16 + lq*4 + r)*49 + col] = cacc[qf][r];
            }
        }
    }
}

// ---------------- z, softmax, videoT per (b,t) -------------------------
__global__ __launch_bounds__(256) void k_zvt(
    const float* __restrict__ Ct0, const float* __restrict__ Ct1,
    const float* __restrict__ gGA, const float* __restrict__ hw,
    const float* __restrict__ video, float* __restrict__ vT)
{
    int bt = blockIdx.x; int t = threadIdx.x;
    __shared__ float sC[49][52];
    __shared__ float salpha[64];
    for (int i = t; i < 49*49; i += 256){
        int p = i / 49, q = i - p*49;
        size_t idx = (size_t)(bt*49 + p)*49 + q;
        sC[p][q] = Ct0[idx] + Ct1[idx];
    }
    __syncthreads();
    if (t < 64){
        float z = -1e30f;
        if (t < 49){
            float ga = gGA[(size_t)bt*49 + t];
            float acc = 0.f;
            for (int q=0;q<49;q++) acc += tanhf(sC[t][q] + ga) * hw[q];
            z = acc;
        }
        float m = z;
        for (int off=32; off; off>>=1) m = fmaxf(m, __shfl_xor(m, off));
        float e = (t<49)? expf(z - m) : 0.f;
        float s = e;
        for (int off=32; off; off>>=1) s += __shfl_xor(s, off);
        salpha[t] = e / s;
    }
    __syncthreads();
    const float* vb = video + (size_t)bt*49*512;
    float a0=0.f, a1=0.f;
    for (int p=0;p<49;p++){
        float al = salpha[p];
        a0 += al * vb[(size_t)p*512 + t];
        a1 += al * vb[(size_t)p*512 + t + 256];
    }
    vT[(size_t)bt*512 + t] = a0;
    vT[(size_t)bt*512 + t + 256] = a1;
}

// ---------------- fused vfea + xproj, 8 bt per block -------------------
__global__ __launch_bounds__(256) void k_xproj2(
    const float* __restrict__ vT, const float* __restrict__ fvW,
    const float* __restrict__ fa,
    const float* __restrict__ la_wih, const float* __restrict__ la_b,
    const float* __restrict__ lv_wih, const float* __restrict__ lv_b,
    float* __restrict__ xp)
{
    int b0 = blockIdx.x*8; int t = threadIdx.x;
    __shared__ float svt[8][512];
    __shared__ float sx[2][8][128];
    for (int i=t;i<4096;i+=256){ int bt=i>>9,k=i&511; svt[bt][k]=vT[(size_t)(b0+bt)*512+k]; }
    for (int i=t;i<1024;i+=256){ int bt=i>>7,k=i&127; sx[0][bt][k]=fa[(size_t)(b0+bt)*128+k]; }
    __syncthreads();
    for (int u=0;u<4;u++){
        int i=t+u*256; int bt=i>>7, n=i&127;
        float acc=0.f;
        for (int k4=0;k4<128;k4++){
            float4 x4 = *(const float4*)&svt[bt][k4*4];
            acc += x4.x*fvW[(k4*4)*128+n] + x4.y*fvW[(k4*4+1)*128+n]
                 + x4.z*fvW[(k4*4+2)*128+n] + x4.w*fvW[(k4*4+3)*128+n];
        }
        sx[1][bt][n]=acc;
    }
    __syncthreads();
    for (int c=0;c<4;c++){
        const float* wih = ((c<2)? la_wih : lv_wih) + (size_t)(c&1)*65536;
        const float* bb  = ((c<2)? la_b   : lv_b  ) + (size_t)(c&1)*512;
        for (int u=0;u<2;u++){
            int n = t + u*256;
            float bvv = bb[n];
            float acc[8];
            #pragma unroll
            for (int bt=0;bt<8;bt++) acc[bt]=bvv;
            for (int k4=0;k4<32;k4++){
                float w0=wih[(k4*4)*512+n], w1=wih[(k4*4+1)*512+n],
                      w2=wih[(k4*4+2)*512+n], w3=wih[(k4*4+3)*512+n];
                #pragma unroll
                for (int bt=0;bt<8;bt++){
                    float4 x4 = *(const float4*)&sx[c>>1][bt][k4*4];
                    acc[bt] += x4.x*w0 + x4.y*w1 + x4.z*w2 + x4.w*w3;
                }
            }
            #pragma unroll
            for (int bt=0;bt<8;bt++)
                xp[((size_t)c*2560 + b0+bt)*512 + n] = acc[bt];
        }
    }
}

// ---------------- persistent bidirectional LSTMs -----------------------
__global__ __launch_bounds__(256) void k_lstm(
    const float* __restrict__ xp, const float* __restrict__ la_whh,
    const float* __restrict__ lv_whh,
    float* __restrict__ lstm_a, float* __restrict__ lstm_v)
{
    int blk = blockIdx.x;
    int c = blk >> 5;
    int chunk = blk & 31;
    int t = threadIdx.x;
    int j  = t & 127;
    int bh = t >> 7;
    const float* whh = ((c<2)? la_whh : lv_whh) + (size_t)(c&1)*128*512;
    float* outp = (c<2)? lstm_a : lstm_v;
    int dir = c & 1;

    __shared__ float hbuf[8][128];
    float cc[4] = {0.f,0.f,0.f,0.f};
    for (int i=t;i<1024;i+=256) ((float*)hbuf)[i] = 0.f;
    __syncthreads();

    for (int s=0; s<10; s++){
        int tt = dir ? (9-s) : s;
        float gi[4], gf[4], gg[4], go[4];
        #pragma unroll
        for (int b=0;b<4;b++){
            int gb = chunk*8 + bh*4 + b;
            const float* xrow = xp + ((size_t)c*2560 + gb*10 + tt)*512;
            gi[b]=xrow[j]; gf[b]=xrow[128+j]; gg[b]=xrow[256+j]; go[b]=xrow[384+j];
        }
        #pragma unroll 4
        for (int k=0;k<128;k++){
            float wi = whh[k*512 + j];
            float wf = whh[k*512 + 128 + j];
            float wg = whh[k*512 + 256 + j];
            float wo = whh[k*512 + 384 + j];
            #pragma unroll
            for (int b=0;b<4;b++){
                float hk = hbuf[bh*4+b][k];
                gi[b] += hk*wi; gf[b] += hk*wf; gg[b] += hk*wg; go[b] += hk*wo;
            }
        }
        __syncthreads();
        #pragma unroll
        for (int b=0;b<4;b++){
            float i_ = sigmoidf_(gi[b]);
            float f_ = sigmoidf_(gf[b]);
            float g_ = tanhf(gg[b]);
            float o_ = sigmoidf_(go[b]);
            cc[b] = f_*cc[b] + i_*g_;
            float h_ = o_*tanhf(cc[b]);
            hbuf[bh*4+b][j] = h_;
            int gb = chunk*8 + bh*4 + b;
            outp[((size_t)gb*10 + tt)*256 + dir*128 + j] = h_;
        }
        __syncthreads();
    }
}

// ---------------- PSP branch projections, 8 bt per block ---------------
__global__ __launch_bounds__(256) void k_psp1(
    const float* __restrict__ lstm_a, const float* __restrict__ lstm_v,
    const float* __restrict__ vL1, const float* __restrict__ vL2,
    const float* __restrict__ aL1, const float* __restrict__ aL2,
    float* __restrict__ vb1, float* __restrict__ vb2,
    float* __restrict__ ab1, float* __restrict__ ab2)
{
    int b0 = blockIdx.x*8; int t = threadIdx.x;
    __shared__ float sa[8][256], sv[8][256];
    for (int i=t;i<2048;i+=256){
        int bt=i>>8, k=i&255;
        sa[bt][k]=lstm_a[(size_t)(b0+bt)*256+k];
        sv[bt][k]=lstm_v[(size_t)(b0+bt)*256+k];
    }
    __syncthreads();
    float a1[8],a2[8],v1[8],v2[8];
    #pragma unroll
    for (int bt=0;bt<8;bt++){ a1[bt]=0;a2[bt]=0;v1[bt]=0;v2[bt]=0; }
    for (int k4=0;k4<64;k4++){
        #pragma unroll
        for (int j=0;j<4;j++){
            int k = k4*4+j;
            float wv1 = vL1[k*256+t], wv2 = vL2[k*256+t];
            float wa1 = aL1[k*256+t], wa2 = aL2[k*256+t];
            #pragma unroll
            for (int bt=0;bt<8;bt++){
                float xv = sv[bt][k], xa = sa[bt][k];
                v1[bt]+=xv*wv1; v2[bt]+=xv*wv2;
                a1[bt]+=xa*wa1; a2[bt]+=xa*wa2;
            }
        }
    }
    #pragma unroll
    for (int bt=0;bt<8;bt++){
        size_t o = (size_t)(b0+bt)*256+t;
        vb1[o]=fmaxf(v1[bt],0.f); vb2[o]=fmaxf(v2[bt],0.f);
        ab1[o]=fmaxf(a1[bt],0.f); ab2[o]=fmaxf(a2[bt],0.f);
    }
}

// ---------------- per-sample PSP attention + psp outputs ---------------
__global__ __launch_bounds__(256) void k_att(
    const float* __restrict__ lstm_a, const float* __restrict__ lstm_v,
    const float* __restrict__ vb1, const float* __restrict__ vb2,
    const float* __restrict__ ab1, const float* __restrict__ ab2,
    const float* __restrict__ thrp,
    float* __restrict__ vpsp, float* __restrict__ apsp)
{
    int b = blockIdx.x, t = threadIdx.x;
    __shared__ float sV2[2560], sA1[2560], sV1[2560], sA2[2560];
    __shared__ float satt[100], s_v2a[100], s_a2v[100];
    size_t base = (size_t)b*2560;
    for (int i=t;i<2560;i+=256){
        sV2[i]=vb2[base+i]; sA1[i]=ab1[base+i];
        sV1[i]=vb1[base+i]; sA2[i]=ab2[base+i];
    }
    __syncthreads();
    if (t < 100){
        int v = t/10, a = t - v*10;
        float acc=0.f;
        for (int k=0;k<256;k++) acc += sV2[v*256+k]*sA1[a*256+k];
        satt[t] = fmaxf(acc*(1.0f/16.0f), 0.f);
    }
    __syncthreads();
    float thr = thrp[0];
    if (t < 10){
        int v = t;
        float rs=0.f; for(int a=0;a<10;a++) rs += satt[v*10+a];
        float inv = 1.f/(rs+1e-8f);
        float tmp[10]; float rs2=0.f;
        for(int a=0;a<10;a++){ float x = satt[v*10+a]*inv; x = (x>thr)?x:0.f; tmp[a]=x; rs2+=x; }
        float inv2 = 1.f/(rs2+1e-8f);
        for(int a=0;a<10;a++) s_v2a[v*10+a] = tmp[a]*inv2;
    } else if (t>=16 && t<26){
        int a = t-16;
        float cs=0.f; for(int v=0;v<10;v++) cs += satt[v*10+a];
        float inv = 1.f/(cs+1e-8f);
        float tmp[10]; float cs2=0.f;
        for(int v=0;v<10;v++){ float x = satt[v*10+a]*inv; x=(x>thr)?x:0.f; tmp[v]=x; cs2+=x; }
        float inv2 = 1.f/(cs2+1e-8f);
        for(int v=0;v<10;v++) s_a2v[a*10+v] = tmp[v]*inv2;
    }
    __syncthreads();
    for (int v=0;v<10;v++){
        float acc = lstm_v[base + v*256 + t];
        #pragma unroll
        for (int a=0;a<10;a++) acc += s_v2a[v*10+a]*sA2[a*256+t];
        vpsp[base + v*256 + t] = acc;
    }
    for (int a=0;a<10;a++){
        float acc = lstm_a[base + a*256 + t];
        #pragma unroll
        for (int v=0;v<10;v++) acc += s_a2v[a*10+v]*sV1[v*256+t];
        apsp[base + a*256 + t] = acc;
    }
}

// ---------------- final: fc + LN + fuse + cosine + MLP, 8 bt/block -----
__global__ __launch_bounds__(256) void k_fin(
    const float* __restrict__ vpsp, const float* __restrict__ apsp,
    const float* __restrict__ vfc, const float* __restrict__ afc,
    const float* __restrict__ ln_g, const float* __restrict__ ln_b,
    const float* __restrict__ L1w, const float* __restrict__ L2w,
    float* __restrict__ dout)
{
    int b0 = blockIdx.x*8;
    int t = threadIdx.x, w = t>>6, lane = t&63;
    __shared__ float sv[8][256], sa[8][256];
    __shared__ float sfu[4][256];
    __shared__ float s64b[4][64];
    for (int i=t;i<2048;i+=256){
        int bt=i>>8, k=i&255;
        sv[bt][k]=vpsp[(size_t)(b0+bt)*256+k];
        sa[bt][k]=apsp[(size_t)(b0+bt)*256+k];
    }
    __syncthreads();
    int c0 = lane*4;
    int bt0 = w*2;
    float vv[2][4], aa[2][4];
    #pragma unroll
    for (int h=0;h<2;h++)
        #pragma unroll
        for (int jj=0;jj<4;jj++){ vv[h][jj]=0.f; aa[h][jj]=0.f; }
    for (int k=0;k<256;k++){
        float4 cv = *(const float4*)&vfc[k*256+c0];
        float4 ca = *(const float4*)&afc[k*256+c0];
        float xv0 = sv[bt0][k], xv1 = sv[bt0+1][k];
        float xa0 = sa[bt0][k], xa1 = sa[bt0+1][k];
        vv[0][0]+=xv0*cv.x; vv[0][1]+=xv0*cv.y; vv[0][2]+=xv0*cv.z; vv[0][3]+=xv0*cv.w;
        vv[1][0]+=xv1*cv.x; vv[1][1]+=xv1*cv.y; vv[1][2]+=xv1*cv.z; vv[1][3]+=xv1*cv.w;
        aa[0][0]+=xa0*ca.x; aa[0][1]+=xa0*ca.y; aa[0][2]+=xa0*ca.z; aa[0][3]+=xa0*ca.w;
        aa[1][0]+=xa1*ca.x; aa[1][1]+=xa1*ca.y; aa[1][2]+=xa1*ca.z; aa[1][3]+=xa1*ca.w;
    }
    float4 g4 = *(const float4*)&ln_g[c0];
    float4 b4 = *(const float4*)&ln_b[c0];
    float gv[4]={g4.x,g4.y,g4.z,g4.w}, bb[4]={b4.x,b4.y,b4.z,b4.w};

    for (int h=0;h<2;h++){
        int row = b0 + bt0 + h;
        float xv[4], xa[4];
        #pragma unroll
        for (int jj=0;jj<4;jj++){ xv[jj]=fmaxf(vv[h][jj],0.f); xa[jj]=fmaxf(aa[h][jj],0.f); }
        float s1 = wred64(xv[0]+xv[1]+xv[2]+xv[3]);
        float s2 = wred64(xv[0]*xv[0]+xv[1]*xv[1]+xv[2]*xv[2]+xv[3]*xv[3]);
        float mu = s1*(1.f/256.f);
        float var = s2*(1.f/256.f) - mu*mu;
        float rs = 1.f/sqrtf(var+1e-6f);
        float vln[4];
        #pragma unroll
        for (int jj=0;jj<4;jj++) vln[jj] = (xv[jj]-mu)*rs*gv[jj]+bb[jj];
        s1 = wred64(xa[0]+xa[1]+xa[2]+xa[3]);
        s2 = wred64(xa[0]*xa[0]+xa[1]*xa[1]+xa[2]*xa[2]+xa[3]*xa[3]);
        mu = s1*(1.f/256.f);
        var = s2*(1.f/256.f) - mu*mu;
        rs = 1.f/sqrtf(var+1e-6f);
        float aln[4];
        #pragma unroll
        for (int jj=0;jj<4;jj++) aln[jj] = (xa[jj]-mu)*rs*gv[jj]+bb[jj];

        float fu[4];
        #pragma unroll
        for (int jj=0;jj<4;jj++){ fu[jj] = 0.5f*(vln[jj]+aln[jj]); dout[(size_t)row*256 + c0 + jj] = fu[jj]; }

        float nv2 = wred64(vln[0]*vln[0]+vln[1]*vln[1]+vln[2]*vln[2]+vln[3]*vln[3]);
        float na2 = wred64(aln[0]*aln[0]+aln[1]*aln[1]+aln[2]*aln[2]+aln[3]*aln[3]);
        float dva = wred64(vln[0]*aln[0]+vln[1]*aln[1]+vln[2]*aln[2]+vln[3]*aln[3]);
        if (lane==0){
            float nv = fmaxf(sqrtf(nv2), 1e-12f);
            float na = fmaxf(sqrtf(na2), 1e-12f);
            dout[729600 + row] = dva/(nv*na);
        }
        *(float4*)&sfu[w][c0] = make_float4(fu[0],fu[1],fu[2],fu[3]);
        float acc = 0.f;
        for (int k4=0;k4<64;k4++){
            float4 f4 = *(const float4*)&sfu[w][k4*4];
            acc += f4.x*L1w[(k4*4)*64+lane] + f4.y*L1w[(k4*4+1)*64+lane]
                 + f4.z*L1w[(k4*4+2)*64+lane] + f4.w*L1w[(k4*4+3)*64+lane];
        }
        s64b[w][lane] = fmaxf(acc, 0.f);
        if (lane < 29){
            float acc2 = 0.f;
            #pragma unroll
            for (int k=0;k<64;k++) acc2 += s64b[w][k]*L2w[k*29+lane];
            dout[655360 + (size_t)row*29 + lane] = acc2;
        }
    }
}

// =======================================================================
extern "C" void kernel_launch(void* const* d_in, const int* in_sizes, int n_in,
                              void* d_out, int out_size, void* d_ws, size_t ws_size,
                              hipStream_t stream) {
    const float* audio  = (const float*)d_in[0];
    const float* video  = (const float*)d_in[1];
    const float* thrp   = (const float*)d_in[2];
    const float* fa_w1  = (const float*)d_in[3];
    const float* fa_w2  = (const float*)d_in[4];
    const float* av_aw  = (const float*)d_in[5];
    const float* av_ab  = (const float*)d_in[6];
    const float* av_vw  = (const float*)d_in[7];
    const float* av_vb  = (const float*)d_in[8];
    const float* av_v2w = (const float*)d_in[9];
    const float* av_gw  = (const float*)d_in[10];
    const float* av_hw  = (const float*)d_in[11];
    const float* fv_w1  = (const float*)d_in[12];
    const float* fv_w2  = (const float*)d_in[13];
    const float* la_wih = (const float*)d_in[14];
    const float* la_whh = (const float*)d_in[15];
    const float* la_b   = (const float*)d_in[16];
    const float* lv_wih = (const float*)d_in[17];
    const float* lv_whh = (const float*)d_in[18];
    const float* lv_b   = (const float*)d_in[19];
    const float* vL1    = (const float*)d_in[20];
    const float* vL2    = (const float*)d_in[21];
    const float* aL1    = (const float*)d_in[22];
    const float* aL2    = (const float*)d_in[23];
    const float* vfc    = (const float*)d_in[24];
    const float* afc    = (const float*)d_in[25];
    const float* ln_g   = (const float*)d_in[26];
    const float* ln_b   = (const float*)d_in[27];
    const float* L1w    = (const float*)d_in[28];
    const float* L2w    = (const float*)d_in[29];
    float* dout = (float*)d_out;
    float* ws = (float*)d_ws;

    // workspace layout (float offsets)
    float* faW  = ws;                 // 16384
    float* fvW  = ws + 16384;         // 65536
    float* fa   = ws + 81920;         // 327680
    float* gGA  = ws + 409600;        // 125440
    float* vT   = ws + 535040;        // 1310720
    float* xp   = ws + 2173440;       // 5242880
    float* la   = ws + 7416320;       // 655360
    float* lv   = ws + 8071680;       // 655360
    float* vb1  = ws + 8727040;
    float* vb2  = ws + 9382400;
    float* ab1  = ws + 10037760;
    float* ab2  = ws + 10693120;
    float* vpsp = ws + 11348480;
    float* apsp = ws + 12003840;
    _Float16* Bh = (_Float16*)(ws + 12659200);  // 262144 halves
    _Float16* Bl = (_Float16*)(ws + 12790272);
    _Float16* Wh = (_Float16*)(ws + 12921344);  // 32768 halves
    _Float16* Wl = (_Float16*)(ws + 12937728);
    float* Cp   = ws + 12954112;      // 2 x 6146560

    k_prep<<<1472, 256, 0, stream>>>(fa_w1, fa_w2, faW, fv_w1, fv_w2, fvW,
                                     av_vw, Bh, Bl, av_v2w, Wh, Wl);
    k_faga<<<640, 256, 0, stream>>>(audio, faW, av_aw, av_ab, av_gw, fa, gGA);
    k_avga_mfma<<<3920, 256, 0, stream>>>(video, Bh, Bl, av_vb, Wh, Wl, Cp);
    k_zvt<<<2560, 256, 0, stream>>>(Cp, Cp + 6146560, gGA, av_hw, video, vT);
    k_xproj2<<<320, 256, 0, stream>>>(vT, fvW, fa, la_wih, la_b, lv_wih, lv_b, xp);
    k_lstm<<<128, 256, 0, stream>>>(xp, la_whh, lv_whh, la, lv);
    k_psp1<<<320, 256, 0, stream>>>(la, lv, vL1, vL2, aL1, aL2, vb1, vb2, ab1, ab2);
    k_att<<<256, 256, 0, stream>>>(la, lv, vb1, vb2, ab1, ab2, thrp, vpsp, apsp);
    k_fin<<<320, 256, 0, stream>>>(vpsp, apsp, vfc, afc, ln_g, ln_b, L1w, L2w, dout);
}

// Round 5
// 741.579 us; speedup vs baseline: 6.0320x; 1.0667x over previous
//
#include <hip/hip_runtime.h>
#include <math.h>

#define DEV __device__ __forceinline__

typedef _Float16 f16x8 __attribute__((ext_vector_type(8)));
typedef _Float16 f16x4 __attribute__((ext_vector_type(4)));
typedef float    f32x4 __attribute__((ext_vector_type(4)));

DEV float sigmoidf_(float x){ return 1.0f/(1.0f + expf(-x)); }

DEV float wred64(float x){
    #pragma unroll
    for (int off=32; off; off>>=1) x += __shfl_xor(x, off);
    return x;
}

// ---------------- prep: faW, fvW, bpack(av_vw), bpack2(v2w) ------------
__global__ __launch_bounds__(256) void k_prep(
    const float* __restrict__ fa_w1, const float* __restrict__ fa_w2, float* __restrict__ faW,
    const float* __restrict__ fv_w1, const float* __restrict__ fv_w2, float* __restrict__ fvW,
    const float* __restrict__ av_vw, _Float16* __restrict__ Bh, _Float16* __restrict__ Bl,
    const float* __restrict__ v2w, _Float16* __restrict__ Wh, _Float16* __restrict__ Wl)
{
    int bid = blockIdx.x, t = threadIdx.x;
    if (bid < 64){                       // faW = fa_w1 @ fa_w2 [128,128] K=256
        int idx = bid*256+t; int m = idx>>7, n = idx&127;
        float acc=0.f;
        for (int k=0;k<256;k++) acc += fa_w1[m*256+k]*fa_w2[k*128+n];
        faW[idx]=acc;
    } else if (bid < 320){               // fvW = fv_w1 @ fv_w2 [512,128] K=256
        int idx = (bid-64)*256+t; int m = idx>>7, n = idx&127;
        float acc=0.f;
        for (int k=0;k<256;k++) acc += fv_w1[m*256+k]*fv_w2[k*128+n];
        fvW[idx]=acc;
    } else if (bid < 1344){              // pack av_vw into B-frag layout
        int o = (bid-320)*256+t;         // 262144
        int j = o & 7, l16 = (o>>3)&15, kg = (o>>7)&3, nf = (o>>9)&31, kt = o>>14;
        int k = kt*32 + kg*8 + j, n = nf*16 + l16;
        float x = av_vw[(size_t)k*512 + n];
        _Float16 h = (_Float16)x;
        Bh[o] = h; Bl[o] = (_Float16)(x - (float)h);
    } else {                             // pack v2w
        int o = (bid-1344)*256+t;        // 32768
        int j = o & 7, l16 = (o>>3)&15, kg = (o>>7)&3, qf = (o>>9)&3, kbg = o>>11;
        int k = kbg*32 + kg*8 + j, q = qf*16 + l16;
        float x = (q < 49) ? v2w[(size_t)k*49 + q] : 0.f;
        _Float16 h = (_Float16)x;
        Wh[o] = h; Wl[o] = (_Float16)(x - (float)h);
    }
}

// ---------------- fused fa + a_h + ga, 4 bt per block ------------------
__global__ __launch_bounds__(256) void k_faga(
    const float* __restrict__ audio, const float* __restrict__ faW,
    const float* __restrict__ av_aw, const float* __restrict__ av_ab,
    const float* __restrict__ av_gw, float* __restrict__ fa, float* __restrict__ gGA)
{
    int b0 = blockIdx.x*4; int t = threadIdx.x;
    __shared__ float sau[4][128], sfa[4][128], sah[4][512];
    for (int i=t;i<512;i+=256){ int bt=i>>7,k=i&127; sau[bt][k]=audio[(size_t)(b0+bt)*128+k]; }
    __syncthreads();
    for (int u=0;u<2;u++){
        int i=t+u*256, bt=i>>7, n=i&127;
        float acc=0.f;
        for (int k4=0;k4<32;k4++){
            float4 x4=*(const float4*)&sau[bt][k4*4];
            acc+=x4.x*faW[(k4*4)*128+n]+x4.y*faW[(k4*4+1)*128+n]
                +x4.z*faW[(k4*4+2)*128+n]+x4.w*faW[(k4*4+3)*128+n];
        }
        sfa[bt][n]=acc; fa[(size_t)(b0+bt)*128+n]=acc;
    }
    __syncthreads();
    for (int u=0;u<2;u++){
        int n=t+u*256;
        float bv=av_ab[n];
        float acc[4]={bv,bv,bv,bv};
        for (int k4=0;k4<32;k4++){
            float w0=av_aw[(k4*4)*512+n], w1=av_aw[(k4*4+1)*512+n],
                  w2=av_aw[(k4*4+2)*512+n], w3=av_aw[(k4*4+3)*512+n];
            #pragma unroll
            for (int bt=0;bt<4;bt++){
                float4 x4=*(const float4*)&sfa[bt][k4*4];
                acc[bt]+=x4.x*w0+x4.y*w1+x4.z*w2+x4.w*w3;
            }
        }
        #pragma unroll
        for (int bt=0;bt<4;bt++) sah[bt][n]=fmaxf(acc[bt],0.f);
    }
    __syncthreads();
    if (t<196){
        int bt=t/49, q=t-bt*49;
        float acc=0.f;
        for (int k=0;k<512;k++) acc+=sah[bt][k]*av_gw[k*49+q];
        gGA[(size_t)(b0+bt)*49+q]=acc;
    }
}

// ---------------- fully fused AVGA: one block per (b,t) ----------------
DEV void cvt4_(float4 v, f16x4& hv, f16x4& lv){
    hv[0]=(_Float16)v.x; lv[0]=(_Float16)(v.x-(float)hv[0]);
    hv[1]=(_Float16)v.y; lv[1]=(_Float16)(v.y-(float)hv[1]);
    hv[2]=(_Float16)v.z; lv[2]=(_Float16)(v.z-(float)hv[2]);
    hv[3]=(_Float16)v.w; lv[3]=(_Float16)(v.w-(float)hv[3]);
}

#define MFMA16(a,b,c) __builtin_amdgcn_mfma_f32_16x16x32_f16(a,b,c,0,0,0)

__global__ __launch_bounds__(256,2) void k_avga_fused(
    const float* __restrict__ video,   // [125440][512]
    const _Float16* __restrict__ Bh, const _Float16* __restrict__ Bl,
    const float* __restrict__ bias,    // av_vb [512]
    const _Float16* __restrict__ Wh, const _Float16* __restrict__ Wl,
    const float* __restrict__ gGA,     // [2560][49]
    const float* __restrict__ hw,      // [49]
    float* __restrict__ vT)            // [2560][512]
{
    __shared__ __align__(16) char smem[67072];
    // GEMM phase: sA dbuf at [0,16384)
    // epilogue:   vh per wave at 16384 + w*8192  [16384,49152)
    // reduce:     partials w*16384                [0,65536)
    // szp at 65536 (float[256]), salpha at 66560 (float[64])
    int bt = blockIdx.x;
    int t = threadIdx.x;
    int lane = t & 63, w = t >> 6;
    int l16 = lane & 15, lq = lane >> 4;
    int lb = lane * 16;

    // A staging coords: thread loads rows am, am+32, 4 consecutive k
    int am = t >> 3, ak = (t & 7) * 4;
    int aoff1 = ((am>>4)*4 + (ak>>3))*256 + (am&15)*16 + (ak&7)*2;
    int am2 = am + 32;
    int aoff2 = ((am2>>4)*4 + (ak>>3))*256 + (am2&15)*16 + (ak&7)*2;
    size_t r1 = (size_t)bt*49 + am;  if (r1 > 125439) r1 = 125439;
    size_t r2 = (size_t)bt*49 + am2; if (r2 > 125439) r2 = 125439;
    const float* Arow1 = video + r1*512 + ak;
    const float* Arow2 = video + r2*512 + ak;

    const f32x4 vzero = {0.f,0.f,0.f,0.f};
    f32x4 acc[4][8];
    #pragma unroll
    for (int p=0;p<4;p++)
        #pragma unroll
        for (int q=0;q<8;q++) acc[p][q] = vzero;

    float4 pa0, pa1;
    // prologue: stage kt=0 into buf 0
    pa0 = *(const float4*)(Arow1);
    pa1 = *(const float4*)(Arow2);
    {
        f16x4 hv, lv;
        char* h = &smem[0];
        cvt4_(pa0, hv, lv);
        *(f16x4*)(h + aoff1) = hv; *(f16x4*)(h + 4096 + aoff1) = lv;
        cvt4_(pa1, hv, lv);
        *(f16x4*)(h + aoff2) = hv; *(f16x4*)(h + 4096 + aoff2) = lv;
    }
    __syncthreads();

    // main K loop: 16 x BK=32; B frags direct from global (L2-resident)
    for (int kt = 0; kt < 16; ++kt){
        int cur = kt & 1;
        bool more = (kt < 15);
        if (more){
            pa0 = *(const float4*)(Arow1 + (kt+1)*32);
            pa1 = *(const float4*)(Arow2 + (kt+1)*32);
        }
        const char* aB = &smem[cur*8192];
        f16x8 ah[4], al[4];
        #pragma unroll
        for (int p=0;p<4;p++){
            ah[p] = *(const f16x8*)(aB + p*1024 + lb);
            al[p] = *(const f16x8*)(aB + 4096 + p*1024 + lb);
        }
        #pragma unroll
        for (int q=0;q<8;q++){
            size_t bo = (size_t)kt*16384 + (size_t)(w*8 + q)*512 + lane*8;
            f16x8 bh  = *(const f16x8*)(Bh + bo);
            f16x8 bl2 = *(const f16x8*)(Bl + bo);
            #pragma unroll
            for (int p=0;p<4;p++){
                acc[p][q] = MFMA16(ah[p], bh,  acc[p][q]);
                acc[p][q] = MFMA16(ah[p], bl2, acc[p][q]);
                acc[p][q] = MFMA16(al[p], bh,  acc[p][q]);
            }
        }
        if (more){
            char* h = &smem[(cur^1)*8192];
            f16x4 hv, lv;
            cvt4_(pa0, hv, lv);
            *(f16x4*)(h + aoff1) = hv; *(f16x4*)(h + 4096 + aoff1) = lv;
            cvt4_(pa1, hv, lv);
            *(f16x4*)(h + aoff2) = hv; *(f16x4*)(h + 4096 + aoff2) = lv;
        }
        __syncthreads();
    }

    // ---- epilogue: per-wave VH (bias+relu, f16 hi/lo) + content MFMA --
    float bv[8];
    #pragma unroll
    for (int q=0;q<8;q++) bv[q] = bias[w*128 + q*16 + l16];

    char* vh = &smem[16384 + w*8192];   // private: hi 4KB + lo 4KB
    f32x4 cacc[4][4];
    #pragma unroll
    for (int p=0;p<4;p++)
        #pragma unroll
        for (int qf=0;qf<4;qf++) cacc[p][qf] = vzero;

    #pragma unroll
    for (int c=0;c<4;c++){
        // write VH chunk (d = w*128 + c*32 .. +32) in A-frag layout
        #pragma unroll
        for (int p=0;p<4;p++)
            #pragma unroll
            for (int qq=0;qq<2;qq++){
                int q = c*2 + qq;
                int offbase = p*1024 + (qq*2 + (l16>>3))*256 + (l16&7)*2;
                #pragma unroll
                for (int r=0;r<4;r++){
                    float x = fmaxf(acc[p][q][r] + bv[q], 0.f);
                    _Float16 hh = (_Float16)x;
                    _Float16 ll = (_Float16)(x - (float)hh);
                    int off = offbase + (lq*4 + r)*16;
                    *(_Float16*)(vh + off)        = hh;
                    *(_Float16*)(vh + 4096 + off) = ll;
                }
            }
        // same-wave read back as A-frags (lgkmcnt ordering, no barrier)
        int kbg = w*4 + c;
        f16x8 vhh[4], vhl[4];
        #pragma unroll
        for (int p=0;p<4;p++){
            vhh[p] = *(const f16x8*)(vh + p*1024 + lb);
            vhl[p] = *(const f16x8*)(vh + 4096 + p*1024 + lb);
        }
        #pragma unroll
        for (int qf=0;qf<4;qf++){
            size_t wo = (size_t)kbg*2048 + qf*512 + lane*8;
            f16x8 wh = *(const f16x8*)(Wh + wo);
            f16x8 wl = *(const f16x8*)(Wl + wo);
            #pragma unroll
            for (int p=0;p<4;p++){
                cacc[p][qf] = MFMA16(vhh[p], wh, cacc[p][qf]);
                cacc[p][qf] = MFMA16(vhh[p], wl, cacc[p][qf]);
                cacc[p][qf] = MFMA16(vhl[p], wh, cacc[p][qf]);
            }
        }
    }

    // ---- cross-wave content reduce ----
    __syncthreads();   // all waves done with sA/vh regions
    float* pw = (float*)&smem[w*16384];
    #pragma unroll
    for (int p=0;p<4;p++)
        #pragma unroll
        for (int qf=0;qf<4;qf++)
            #pragma unroll
            for (int r=0;r<4;r++)
                pw[(p*16 + lq*4 + r)*64 + qf*16 + l16] = cacc[p][qf][r];
    __syncthreads();
    float* cb = (float*)&smem[0];
    for (int i=t; i<4096; i+=256)
        cb[i] = cb[i] + cb[4096+i] + cb[8192+i] + cb[12288+i];
    __syncthreads();

    // ---- z = sum_q tanh(content+ga)*hw ; softmax ; weighted sum -------
    float* szp    = (float*)&smem[65536];
    float* salpha = (float*)&smem[66560];
    if (t < 196){
        int p = t >> 2, ds = t & 3;
        float ga = gGA[(size_t)bt*49 + p];
        float part = 0.f;
        for (int q = ds*13; q < ds*13+13 && q < 49; q++)
            part += tanhf(cb[p*64 + q] + ga) * hw[q];
        szp[t] = part;
    }
    __syncthreads();
    if (t < 64){
        float z = (t<49) ? (szp[t*4]+szp[t*4+1]+szp[t*4+2]+szp[t*4+3]) : -1e30f;
        float m = z;
        #pragma unroll
        for (int off=32; off; off>>=1) m = fmaxf(m, __shfl_xor(m, off));
        float e = (t<49)? expf(z - m) : 0.f;
        float s = e;
        #pragma unroll
        for (int off=32; off; off>>=1) s += __shfl_xor(s, off);
        salpha[t] = e / s;
    }
    __syncthreads();
    const float* vb = video + (size_t)bt*49*512;
    #pragma unroll
    for (int u=0;u<2;u++){
        int d = t + u*256;
        float a0 = 0.f;
        for (int p=0;p<49;p++) a0 += salpha[p] * vb[(size_t)p*512 + d];
        vT[(size_t)bt*512 + d] = a0;
    }
}

// ---------------- fused vfea + xproj, 8 bt per block -------------------
__global__ __launch_bounds__(256) void k_xproj2(
    const float* __restrict__ vT, const float* __restrict__ fvW,
    const float* __restrict__ fa,
    const float* __restrict__ la_wih, const float* __restrict__ la_b,
    const float* __restrict__ lv_wih, const float* __restrict__ lv_b,
    float* __restrict__ xp)
{
    int b0 = blockIdx.x*8; int t = threadIdx.x;
    __shared__ float svt[8][512];
    __shared__ float sx[2][8][128];
    for (int i=t;i<4096;i+=256){ int bt=i>>9,k=i&511; svt[bt][k]=vT[(size_t)(b0+bt)*512+k]; }
    for (int i=t;i<1024;i+=256){ int bt=i>>7,k=i&127; sx[0][bt][k]=fa[(size_t)(b0+bt)*128+k]; }
    __syncthreads();
    for (int u=0;u<4;u++){
        int i=t+u*256; int bt=i>>7, n=i&127;
        float acc=0.f;
        for (int k4=0;k4<128;k4++){
            float4 x4 = *(const float4*)&svt[bt][k4*4];
            acc += x4.x*fvW[(k4*4)*128+n] + x4.y*fvW[(k4*4+1)*128+n]
                 + x4.z*fvW[(k4*4+2)*128+n] + x4.w*fvW[(k4*4+3)*128+n];
        }
        sx[1][bt][n]=acc;
    }
    __syncthreads();
    for (int c=0;c<4;c++){
        const float* wih = ((c<2)? la_wih : lv_wih) + (size_t)(c&1)*65536;
        const float* bb  = ((c<2)? la_b   : lv_b  ) + (size_t)(c&1)*512;
        for (int u=0;u<2;u++){
            int n = t + u*256;
            float bvv = bb[n];
            float acc[8];
            #pragma unroll
            for (int bt=0;bt<8;bt++) acc[bt]=bvv;
            for (int k4=0;k4<32;k4++){
                float w0=wih[(k4*4)*512+n], w1=wih[(k4*4+1)*512+n],
                      w2=wih[(k4*4+2)*512+n], w3=wih[(k4*4+3)*512+n];
                #pragma unroll
                for (int bt=0;bt<8;bt++){
                    float4 x4 = *(const float4*)&sx[c>>1][bt][k4*4];
                    acc[bt] += x4.x*w0 + x4.y*w1 + x4.z*w2 + x4.w*w3;
                }
            }
            #pragma unroll
            for (int bt=0;bt<8;bt++)
                xp[((size_t)c*2560 + b0+bt)*512 + n] = acc[bt];
        }
    }
}

// ---------------- persistent bidirectional LSTMs (256 blocks) ----------
__global__ __launch_bounds__(256) void k_lstm(
    const float* __restrict__ xp, const float* __restrict__ la_whh,
    const float* __restrict__ lv_whh,
    float* __restrict__ lstm_a, float* __restrict__ lstm_v)
{
    int blk = blockIdx.x;       // 256 blocks
    int c = blk >> 6;           // combo: 0 a-fwd, 1 a-bwd, 2 v-fwd, 3 v-bwd
    int chunk = blk & 63;       // batch chunk of 4
    int t = threadIdx.x;
    int j  = t & 127;
    int bh = t >> 7;            // 0..1, owns 2 samples each
    const float* whh = ((c<2)? la_whh : lv_whh) + (size_t)(c&1)*128*512;
    float* outp = (c<2)? lstm_a : lstm_v;
    int dir = c & 1;

    __shared__ float hbuf[4][128];
    float cc[2] = {0.f,0.f};
    for (int i=t;i<512;i+=256) ((float*)hbuf)[i] = 0.f;
    __syncthreads();

    for (int s=0; s<10; s++){
        int tt = dir ? (9-s) : s;
        float gi[2], gf[2], gg[2], go[2];
        #pragma unroll
        for (int b=0;b<2;b++){
            int gb = chunk*4 + bh*2 + b;
            const float* xrow = xp + ((size_t)c*2560 + gb*10 + tt)*512;
            gi[b]=xrow[j]; gf[b]=xrow[128+j]; gg[b]=xrow[256+j]; go[b]=xrow[384+j];
        }
        #pragma unroll 4
        for (int k=0;k<128;k++){
            float wi = whh[k*512 + j];
            float wf = whh[k*512 + 128 + j];
            float wg = whh[k*512 + 256 + j];
            float wo = whh[k*512 + 384 + j];
            #pragma unroll
            for (int b=0;b<2;b++){
                float hk = hbuf[bh*2+b][k];
                gi[b] += hk*wi; gf[b] += hk*wf; gg[b] += hk*wg; go[b] += hk*wo;
            }
        }
        __syncthreads();
        #pragma unroll
        for (int b=0;b<2;b++){
            float i_ = sigmoidf_(gi[b]);
            float f_ = sigmoidf_(gf[b]);
            float g_ = tanhf(gg[b]);
            float o_ = sigmoidf_(go[b]);
            cc[b] = f_*cc[b] + i_*g_;
            float h_ = o_*tanhf(cc[b]);
            hbuf[bh*2+b][j] = h_;
            int gb = chunk*4 + bh*2 + b;
            outp[((size_t)gb*10 + tt)*256 + dir*128 + j] = h_;
        }
        __syncthreads();
    }
}

// ---------------- PSP branch projections, 8 bt per block ---------------
__global__ __launch_bounds__(256) void k_psp1(
    const float* __restrict__ lstm_a, const float* __restrict__ lstm_v,
    const float* __restrict__ vL1, const float* __restrict__ vL2,
    const float* __restrict__ aL1, const float* __restrict__ aL2,
    float* __restrict__ vb1, float* __restrict__ vb2,
    float* __restrict__ ab1, float* __restrict__ ab2)
{
    int b0 = blockIdx.x*8; int t = threadIdx.x;
    __shared__ float sa[8][256], sv[8][256];
    for (int i=t;i<2048;i+=256){
        int bt=i>>8, k=i&255;
        sa[bt][k]=lstm_a[(size_t)(b0+bt)*256+k];
        sv[bt][k]=lstm_v[(size_t)(b0+bt)*256+k];
    }
    __syncthreads();
    float a1[8],a2[8],v1[8],v2[8];
    #pragma unroll
    for (int bt=0;bt<8;bt++){ a1[bt]=0;a2[bt]=0;v1[bt]=0;v2[bt]=0; }
    for (int k4=0;k4<64;k4++){
        #pragma unroll
        for (int j=0;j<4;j++){
            int k = k4*4+j;
            float wv1 = vL1[k*256+t], wv2 = vL2[k*256+t];
            float wa1 = aL1[k*256+t], wa2 = aL2[k*256+t];
            #pragma unroll
            for (int bt=0;bt<8;bt++){
                float xv = sv[bt][k], xa = sa[bt][k];
                v1[bt]+=xv*wv1; v2[bt]+=xv*wv2;
                a1[bt]+=xa*wa1; a2[bt]+=xa*wa2;
            }
        }
    }
    #pragma unroll
    for (int bt=0;bt<8;bt++){
        size_t o = (size_t)(b0+bt)*256+t;
        vb1[o]=fmaxf(v1[bt],0.f); vb2[o]=fmaxf(v2[bt],0.f);
        ab1[o]=fmaxf(a1[bt],0.f); ab2[o]=fmaxf(a2[bt],0.f);
    }
}

// ---------------- per-sample PSP attention + psp outputs ---------------
__global__ __launch_bounds__(256) void k_att(
    const float* __restrict__ lstm_a, const float* __restrict__ lstm_v,
    const float* __restrict__ vb1, const float* __restrict__ vb2,
    const float* __restrict__ ab1, const float* __restrict__ ab2,
    const float* __restrict__ thrp,
    float* __restrict__ vpsp, float* __restrict__ apsp)
{
    int b = blockIdx.x, t = threadIdx.x;
    __shared__ float sV2[2560], sA1[2560], sV1[2560], sA2[2560];
    __shared__ float satt[100], s_v2a[100], s_a2v[100];
    size_t base = (size_t)b*2560;
    for (int i=t;i<2560;i+=256){
        sV2[i]=vb2[base+i]; sA1[i]=ab1[base+i];
        sV1[i]=vb1[base+i]; sA2[i]=ab2[base+i];
    }
    __syncthreads();
    if (t < 100){
        int v = t/10, a = t - v*10;
        float acc=0.f;
        for (int k=0;k<256;k++) acc += sV2[v*256+k]*sA1[a*256+k];
        satt[t] = fmaxf(acc*(1.0f/16.0f), 0.f);
    }
    __syncthreads();
    float thr = thrp[0];
    if (t < 10){
        int v = t;
        float rs=0.f; for(int a=0;a<10;a++) rs += satt[v*10+a];
        float inv = 1.f/(rs+1e-8f);
        float tmp[10]; float rs2=0.f;
        for(int a=0;a<10;a++){ float x = satt[v*10+a]*inv; x = (x>thr)?x:0.f; tmp[a]=x; rs2+=x; }
        float inv2 = 1.f/(rs2+1e-8f);
        for(int a=0;a<10;a++) s_v2a[v*10+a] = tmp[a]*inv2;
    } else if (t>=16 && t<26){
        int a = t-16;
        float cs=0.f; for(int v=0;v<10;v++) cs += satt[v*10+a];
        float inv = 1.f/(cs+1e-8f);
        float tmp[10]; float cs2=0.f;
        for(int v=0;v<10;v++){ float x = satt[v*10+a]*inv; x=(x>thr)?x:0.f; tmp[v]=x; cs2+=x; }
        float inv2 = 1.f/(cs2+1e-8f);
        for(int v=0;v<10;v++) s_a2v[a*10+v] = tmp[v]*inv2;
    }
    __syncthreads();
    for (int v=0;v<10;v++){
        float acc = lstm_v[base + v*256 + t];
        #pragma unroll
        for (int a=0;a<10;a++) acc += s_v2a[v*10+a]*sA2[a*256+t];
        vpsp[base + v*256 + t] = acc;
    }
    for (int a=0;a<10;a++){
        float acc = lstm_a[base + a*256 + t];
        #pragma unroll
        for (int v=0;v<10;v++) acc += s_a2v[a*10+v]*sV1[v*256+t];
        apsp[base + a*256 + t] = acc;
    }
}

// ---------------- final: fc + LN + fuse + cosine + MLP, 8 bt/block -----
__global__ __launch_bounds__(256) void k_fin(
    const float* __restrict__ vpsp, const float* __restrict__ apsp,
    const float* __restrict__ vfc, const float* __restrict__ afc,
    const float* __restrict__ ln_g, const float* __restrict__ ln_b,
    const float* __restrict__ L1w, const float* __restrict__ L2w,
    float* __restrict__ dout)
{
    int b0 = blockIdx.x*8;
    int t = threadIdx.x, w = t>>6, lane = t&63;
    __shared__ float sv[8][256], sa[8][256];
    __shared__ float sfu[4][256];
    __shared__ float s64b[4][64];
    for (int i=t;i<2048;i+=256){
        int bt=i>>8, k=i&255;
        sv[bt][k]=vpsp[(size_t)(b0+bt)*256+k];
        sa[bt][k]=apsp[(size_t)(b0+bt)*256+k];
    }
    __syncthreads();
    int c0 = lane*4;
    int bt0 = w*2;
    float vv[2][4], aa[2][4];
    #pragma unroll
    for (int h=0;h<2;h++)
        #pragma unroll
        for (int jj=0;jj<4;jj++){ vv[h][jj]=0.f; aa[h][jj]=0.f; }
    for (int k=0;k<256;k++){
        float4 cv = *(const float4*)&vfc[k*256+c0];
        float4 ca = *(const float4*)&afc[k*256+c0];
        float xv0 = sv[bt0][k], xv1 = sv[bt0+1][k];
        float xa0 = sa[bt0][k], xa1 = sa[bt0+1][k];
        vv[0][0]+=xv0*cv.x; vv[0][1]+=xv0*cv.y; vv[0][2]+=xv0*cv.z; vv[0][3]+=xv0*cv.w;
        vv[1][0]+=xv1*cv.x; vv[1][1]+=xv1*cv.y; vv[1][2]+=xv1*cv.z; vv[1][3]+=xv1*cv.w;
        aa[0][0]+=xa0*ca.x; aa[0][1]+=xa0*ca.y; aa[0][2]+=xa0*ca.z; aa[0][3]+=xa0*ca.w;
        aa[1][0]+=xa1*ca.x; aa[1][1]+=xa1*ca.y; aa[1][2]+=xa1*ca.z; aa[1][3]+=xa1*ca.w;
    }
    float4 g4 = *(const float4*)&ln_g[c0];
    float4 b4 = *(const float4*)&ln_b[c0];
    float gv[4]={g4.x,g4.y,g4.z,g4.w}, bb[4]={b4.x,b4.y,b4.z,b4.w};

    for (int h=0;h<2;h++){
        int row = b0 + bt0 + h;
        float xv[4], xa[4];
        #pragma unroll
        for (int jj=0;jj<4;jj++){ xv[jj]=fmaxf(vv[h][jj],0.f); xa[jj]=fmaxf(aa[h][jj],0.f); }
        float s1 = wred64(xv[0]+xv[1]+xv[2]+xv[3]);
        float s2 = wred64(xv[0]*xv[0]+xv[1]*xv[1]+xv[2]*xv[2]+xv[3]*xv[3]);
        float mu = s1*(1.f/256.f);
        float var = s2*(1.f/256.f) - mu*mu;
        float rs = 1.f/sqrtf(var+1e-6f);
        float vln[4];
        #pragma unroll
        for (int jj=0;jj<4;jj++) vln[jj] = (xv[jj]-mu)*rs*gv[jj]+bb[jj];
        s1 = wred64(xa[0]+xa[1]+xa[2]+xa[3]);
        s2 = wred64(xa[0]*xa[0]+xa[1]*xa[1]+xa[2]*xa[2]+xa[3]*xa[3]);
        mu = s1*(1.f/256.f);
        var = s2*(1.f/256.f) - mu*mu;
        rs = 1.f/sqrtf(var+1e-6f);
        float aln[4];
        #pragma unroll
        for (int jj=0;jj<4;jj++) aln[jj] = (xa[jj]-mu)*rs*gv[jj]+bb[jj];

        float fu[4];
        #pragma unroll
        for (int jj=0;jj<4;jj++){ fu[jj] = 0.5f*(vln[jj]+aln[jj]); dout[(size_t)row*256 + c0 + jj] = fu[jj]; }

        float nv2 = wred64(vln[0]*vln[0]+vln[1]*vln[1]+vln[2]*vln[2]+vln[3]*vln[3]);
        float na2 = wred64(aln[0]*aln[0]+aln[1]*aln[1]+aln[2]*aln[2]+aln[3]*aln[3]);
        float dva = wred64(vln[0]*aln[0]+vln[1]*aln[1]+vln[2]*aln[2]+vln[3]*aln[3]);
        if (lane==0){
            float nv = fmaxf(sqrtf(nv2), 1e-12f);
            float na = fmaxf(sqrtf(na2), 1e-12f);
            dout[729600 + row] = dva/(nv*na);
        }
        *(float4*)&sfu[w][c0] = make_float4(fu[0],fu[1],fu[2],fu[3]);
        float acc = 0.f;
        for (int k4=0;k4<64;k4++){
            float4 f4 = *(const float4*)&sfu[w][k4*4];
            acc += f4.x*L1w[(k4*4)*64+lane] + f4.y*L1w[(k4*4+1)*64+lane]
                 + f4.z*L1w[(k4*4+2)*64+lane] + f4.w*L1w[(k4*4+3)*64+lane];
        }
        s64b[w][lane] = fmaxf(acc, 0.f);
        if (lane < 29){
            float acc2 = 0.f;
            #pragma unroll
            for (int k=0;k<64;k++) acc2 += s64b[w][k]*L2w[k*29+lane];
            dout[655360 + (size_t)row*29 + lane] = acc2;
        }
    }
}

// =======================================================================
extern "C" void kernel_launch(void* const* d_in, const int* in_sizes, int n_in,
                              void* d_out, int out_size, void* d_ws, size_t ws_size,
                              hipStream_t stream) {
    const float* audio  = (const float*)d_in[0];
    const float* video  = (const float*)d_in[1];
    const float* thrp   = (const float*)d_in[2];
    const float* fa_w1  = (const float*)d_in[3];
    const float* fa_w2  = (const float*)d_in[4];
    const float* av_aw  = (const float*)d_in[5];
    const float* av_ab  = (const float*)d_in[6];
    const float* av_vw  = (const float*)d_in[7];
    const float* av_vb  = (const float*)d_in[8];
    const float* av_v2w = (const float*)d_in[9];
    const float* av_gw  = (const float*)d_in[10];
    const float* av_hw  = (const float*)d_in[11];
    const float* fv_w1  = (const float*)d_in[12];
    const float* fv_w2  = (const float*)d_in[13];
    const float* la_wih = (const float*)d_in[14];
    const float* la_whh = (const float*)d_in[15];
    const float* la_b   = (const float*)d_in[16];
    const float* lv_wih = (const float*)d_in[17];
    const float* lv_whh = (const float*)d_in[18];
    const float* lv_b   = (const float*)d_in[19];
    const float* vL1    = (const float*)d_in[20];
    const float* vL2    = (const float*)d_in[21];
    const float* aL1    = (const float*)d_in[22];
    const float* aL2    = (const float*)d_in[23];
    const float* vfc    = (const float*)d_in[24];
    const float* afc    = (const float*)d_in[25];
    const float* ln_g   = (const float*)d_in[26];
    const float* ln_b   = (const float*)d_in[27];
    const float* L1w    = (const float*)d_in[28];
    const float* L2w    = (const float*)d_in[29];
    float* dout = (float*)d_out;
    float* ws = (float*)d_ws;

    // workspace layout (float offsets)
    float* faW  = ws;                 // 16384
    float* fvW  = ws + 16384;         // 65536
    float* fa   = ws + 81920;         // 327680
    float* gGA  = ws + 409600;        // 125440
    float* vT   = ws + 535040;        // 1310720
    float* xp   = ws + 2173440;       // 5242880
    float* la   = ws + 7416320;       // 655360
    float* lv   = ws + 8071680;       // 655360
    float* vb1  = ws + 8727040;
    float* vb2  = ws + 9382400;
    float* ab1  = ws + 10037760;
    float* ab2  = ws + 10693120;
    float* vpsp = ws + 11348480;
    float* apsp = ws + 12003840;
    _Float16* Bh = (_Float16*)(ws + 12659200);  // 262144 halves
    _Float16* Bl = (_Float16*)(ws + 12790272);
    _Float16* Wh = (_Float16*)(ws + 12921344);  // 32768 halves
    _Float16* Wl = (_Float16*)(ws + 12937728);

    k_prep<<<1472, 256, 0, stream>>>(fa_w1, fa_w2, faW, fv_w1, fv_w2, fvW,
                                     av_vw, Bh, Bl, av_v2w, Wh, Wl);
    k_faga<<<640, 256, 0, stream>>>(audio, faW, av_aw, av_ab, av_gw, fa, gGA);
    k_avga_fused<<<2560, 256, 0, stream>>>(video, Bh, Bl, av_vb, Wh, Wl,
                                           gGA, av_hw, vT);
    k_xproj2<<<320, 256, 0, stream>>>(vT, fvW, fa, la_wih, la_b, lv_wih, lv_b, xp);
    k_lstm<<<256, 256, 0, stream>>>(xp, la_whh, lv_whh, la, lv);
    k_psp1<<<320, 256, 0, stream>>>(la, lv, vL1, vL2, aL1, aL2, vb1, vb2, ab1, ab2);
    k_att<<<256, 256, 0, stream>>>(la, lv, vb1, vb2, ab1, ab2, thrp, vpsp, apsp);
    k_fin<<<320, 256, 0, stream>>>(vpsp, apsp, vfc, afc, ln_g, ln_b, L1w, L2w, dout);
}